// Round 1
// baseline (1371.296 us; speedup 1.0000x reference)
//
#include <hip/hip_runtime.h>
#include <cstdint>

#define HD 128   // HDIM
#define ED 32    // EDIM
#define TE 64    // edges / nodes per block tile
#define KC 32    // K chunk staged in LDS

// ---------------------------------------------------------------- zero ws
__global__ __launch_bounds__(256) void zero_f32(float4* p, long n4) {
    long i = (long)blockIdx.x * blockDim.x + threadIdx.x;
    const long stride = (long)gridDim.x * blockDim.x;
    const float4 z = make_float4(0.f, 0.f, 0.f, 0.f);
    for (; i < n4; i += stride) p[i] = z;
}

// ---------------------------------------------------------------- edges
// block: 256 threads, one tile of TE=64 edges.
// thread (og = t&31, eg = t>>5) owns outputs o0=og*4.. (4) x edges e0=eg*8.. (8)
__global__ __launch_bounds__(256, 2)
void edge_msg_kernel(const float* __restrict__ h,
                     const int*   __restrict__ eidx,   // [2][E]
                     const float* __restrict__ ea,     // [E][ED]
                     const float* __restrict__ w1,     // [2*HD+ED][HD]
                     const float* __restrict__ b1,     // [HD]
                     const float* __restrict__ w2,     // [HD][HD]
                     const float* __restrict__ b2,     // [HD]
                     float*       __restrict__ agg,    // [N][HD]
                     int E)
{
    __shared__ float sA[KC][TE];        // m_in chunk, K-major
    __shared__ float sW[KC][HD];        // weight chunk
    __shared__ float sT[HD][TE + 1];    // relu(layer1) tile, K-major (+1 pad)
    __shared__ int   sSrc[TE];
    __shared__ int   sDst[TE];

    const int t  = threadIdx.x;
    const int og = t & 31;
    const int eg = t >> 5;
    const int e0 = eg * 8;
    const int o0 = og * 4;
    const int ebase = blockIdx.x * TE;

    if (t < TE) {
        int e  = ebase + t;
        int ec = (e < E) ? e : (E - 1);
        sSrc[t] = eidx[ec];
        sDst[t] = eidx[E + ec];
    }
    __syncthreads();

    const int ge = t >> 2;            // gather: edge index within tile
    const int dq = (t & 3) * 8;       // gather: k offset within chunk
    const int wk = t >> 3;            // weight load: k row within chunk
    const int wo = (t & 7) * 16;      // weight load: out-col offset
    const int gec = (ebase + ge < E) ? (ebase + ge) : (E - 1);

    float acc[4][8];
#pragma unroll
    for (int i = 0; i < 4; ++i)
#pragma unroll
        for (int j = 0; j < 8; ++j) acc[i][j] = 0.f;

    // ---------------- layer 1 : K = 2*HD + ED = 288 ----------------
#pragma unroll 1
    for (int kb = 0; kb < 2 * HD + ED; kb += KC) {
        const float* ap;
        if (kb < HD)          ap = h  + (size_t)sSrc[ge] * HD + (kb + dq);
        else if (kb < 2 * HD) ap = h  + (size_t)sDst[ge] * HD + (kb - HD + dq);
        else                  ap = ea + (size_t)gec * ED + (kb - 2 * HD + dq);
        const float4 a0 = *(const float4*)(ap);
        const float4 a1 = *(const float4*)(ap + 4);
        const float* wp = w1 + (size_t)(kb + wk) * HD + wo;
        const float4 q0 = *(const float4*)(wp);
        const float4 q1 = *(const float4*)(wp + 4);
        const float4 q2 = *(const float4*)(wp + 8);
        const float4 q3 = *(const float4*)(wp + 12);
        __syncthreads();                 // previous GEMM chunk done reading sA/sW
        sA[dq + 0][ge] = a0.x; sA[dq + 1][ge] = a0.y;
        sA[dq + 2][ge] = a0.z; sA[dq + 3][ge] = a0.w;
        sA[dq + 4][ge] = a1.x; sA[dq + 5][ge] = a1.y;
        sA[dq + 6][ge] = a1.z; sA[dq + 7][ge] = a1.w;
        *(float4*)&sW[wk][wo +  0] = q0;
        *(float4*)&sW[wk][wo +  4] = q1;
        *(float4*)&sW[wk][wo +  8] = q2;
        *(float4*)&sW[wk][wo + 12] = q3;
        __syncthreads();
#pragma unroll
        for (int k = 0; k < KC; ++k) {
            const float4 av0 = *(const float4*)&sA[k][e0];
            const float4 av1 = *(const float4*)&sA[k][e0 + 4];
            const float4 wv  = *(const float4*)&sW[k][o0];
            const float a8[8] = {av0.x, av0.y, av0.z, av0.w,
                                 av1.x, av1.y, av1.z, av1.w};
            const float w4[4] = {wv.x, wv.y, wv.z, wv.w};
#pragma unroll
            for (int oi = 0; oi < 4; ++oi)
#pragma unroll
                for (int ej = 0; ej < 8; ++ej)
                    acc[oi][ej] = fmaf(w4[oi], a8[ej], acc[oi][ej]);
        }
    }

    // bias + relu -> sT ; reset acc for layer 2
    {
        const float4 bb = *(const float4*)&b1[o0];
        const float b4[4] = {bb.x, bb.y, bb.z, bb.w};
#pragma unroll
        for (int oi = 0; oi < 4; ++oi)
#pragma unroll
            for (int ej = 0; ej < 8; ++ej) {
                float v = acc[oi][ej] + b4[oi];
                sT[o0 + oi][e0 + ej] = (v > 0.f) ? v : 0.f;
                acc[oi][ej] = 0.f;
            }
    }
    __syncthreads();

    // ---------------- layer 2 : K = HD = 128 ----------------
#pragma unroll 1
    for (int kb = 0; kb < HD; kb += KC) {
        const float* wp = w2 + (size_t)(kb + wk) * HD + wo;
        const float4 q0 = *(const float4*)(wp);
        const float4 q1 = *(const float4*)(wp + 4);
        const float4 q2 = *(const float4*)(wp + 8);
        const float4 q3 = *(const float4*)(wp + 12);
        __syncthreads();
        *(float4*)&sW[wk][wo +  0] = q0;
        *(float4*)&sW[wk][wo +  4] = q1;
        *(float4*)&sW[wk][wo +  8] = q2;
        *(float4*)&sW[wk][wo + 12] = q3;
        __syncthreads();
#pragma unroll
        for (int k = 0; k < KC; ++k) {
            const float* tp = &sT[kb + k][e0];
            const float4 wv = *(const float4*)&sW[k][o0];
            const float w4[4] = {wv.x, wv.y, wv.z, wv.w};
            float a8[8];
#pragma unroll
            for (int ej = 0; ej < 8; ++ej) a8[ej] = tp[ej];
#pragma unroll
            for (int oi = 0; oi < 4; ++oi)
#pragma unroll
                for (int ej = 0; ej < 8; ++ej)
                    acc[oi][ej] = fmaf(w4[oi], a8[ej], acc[oi][ej]);
        }
    }

    // bias + scatter-add into agg
    {
        const float4 bb = *(const float4*)&b2[o0];
        const float b4[4] = {bb.x, bb.y, bb.z, bb.w};
#pragma unroll
        for (int ej = 0; ej < 8; ++ej) {
            const int e = e0 + ej;
            if (ebase + e < E) {
                float* dstp = agg + (size_t)sDst[e] * HD + o0;
#pragma unroll
                for (int oi = 0; oi < 4; ++oi)
                    atomicAdd(dstp + oi, acc[oi][ej] + b4[oi]);
            }
        }
    }
}

// ---------------------------------------------------------------- nodes
__global__ __launch_bounds__(256, 2)
void node_upd_kernel(const float* __restrict__ h,
                     const float* __restrict__ agg,
                     const float* __restrict__ w1,    // [2*HD][HD]
                     const float* __restrict__ b1,
                     const float* __restrict__ w2,    // [HD][HD]
                     const float* __restrict__ b2,
                     const float* __restrict__ gamma,
                     const float* __restrict__ beta,
                     float*       __restrict__ out,
                     int N)
{
    __shared__ float sA[KC][TE];
    __shared__ float sW[KC][HD];
    __shared__ float sT[HD][TE + 1];

    const int t  = threadIdx.x;
    const int og = t & 31;
    const int eg = t >> 5;
    const int e0 = eg * 8;
    const int o0 = og * 4;
    const int vbase = blockIdx.x * TE;

    const int ge = t >> 2;
    const int dq = (t & 3) * 8;
    const int wk = t >> 3;
    const int wo = (t & 7) * 16;
    const int gvc = (vbase + ge < N) ? (vbase + ge) : (N - 1);

    float acc[4][8];
#pragma unroll
    for (int i = 0; i < 4; ++i)
#pragma unroll
        for (int j = 0; j < 8; ++j) acc[i][j] = 0.f;

    // ---------------- layer 1 : K = 2*HD = 256 ----------------
#pragma unroll 1
    for (int kb = 0; kb < 2 * HD; kb += KC) {
        const float* ap = (kb < HD)
            ? (h   + (size_t)gvc * HD + (kb + dq))
            : (agg + (size_t)gvc * HD + (kb - HD + dq));
        const float4 a0 = *(const float4*)(ap);
        const float4 a1 = *(const float4*)(ap + 4);
        const float* wp = w1 + (size_t)(kb + wk) * HD + wo;
        const float4 q0 = *(const float4*)(wp);
        const float4 q1 = *(const float4*)(wp + 4);
        const float4 q2 = *(const float4*)(wp + 8);
        const float4 q3 = *(const float4*)(wp + 12);
        __syncthreads();
        sA[dq + 0][ge] = a0.x; sA[dq + 1][ge] = a0.y;
        sA[dq + 2][ge] = a0.z; sA[dq + 3][ge] = a0.w;
        sA[dq + 4][ge] = a1.x; sA[dq + 5][ge] = a1.y;
        sA[dq + 6][ge] = a1.z; sA[dq + 7][ge] = a1.w;
        *(float4*)&sW[wk][wo +  0] = q0;
        *(float4*)&sW[wk][wo +  4] = q1;
        *(float4*)&sW[wk][wo +  8] = q2;
        *(float4*)&sW[wk][wo + 12] = q3;
        __syncthreads();
#pragma unroll
        for (int k = 0; k < KC; ++k) {
            const float4 av0 = *(const float4*)&sA[k][e0];
            const float4 av1 = *(const float4*)&sA[k][e0 + 4];
            const float4 wv  = *(const float4*)&sW[k][o0];
            const float a8[8] = {av0.x, av0.y, av0.z, av0.w,
                                 av1.x, av1.y, av1.z, av1.w};
            const float w4[4] = {wv.x, wv.y, wv.z, wv.w};
#pragma unroll
            for (int oi = 0; oi < 4; ++oi)
#pragma unroll
                for (int ej = 0; ej < 8; ++ej)
                    acc[oi][ej] = fmaf(w4[oi], a8[ej], acc[oi][ej]);
        }
    }

    {
        const float4 bb = *(const float4*)&b1[o0];
        const float b4[4] = {bb.x, bb.y, bb.z, bb.w};
#pragma unroll
        for (int oi = 0; oi < 4; ++oi)
#pragma unroll
            for (int ej = 0; ej < 8; ++ej) {
                float v = acc[oi][ej] + b4[oi];
                sT[o0 + oi][e0 + ej] = (v > 0.f) ? v : 0.f;
                acc[oi][ej] = 0.f;
            }
    }
    __syncthreads();

    // ---------------- layer 2 : K = HD ----------------
#pragma unroll 1
    for (int kb = 0; kb < HD; kb += KC) {
        const float* wp = w2 + (size_t)(kb + wk) * HD + wo;
        const float4 q0 = *(const float4*)(wp);
        const float4 q1 = *(const float4*)(wp + 4);
        const float4 q2 = *(const float4*)(wp + 8);
        const float4 q3 = *(const float4*)(wp + 12);
        __syncthreads();
        *(float4*)&sW[wk][wo +  0] = q0;
        *(float4*)&sW[wk][wo +  4] = q1;
        *(float4*)&sW[wk][wo +  8] = q2;
        *(float4*)&sW[wk][wo + 12] = q3;
        __syncthreads();
#pragma unroll
        for (int k = 0; k < KC; ++k) {
            const float* tp = &sT[kb + k][e0];
            const float4 wv = *(const float4*)&sW[k][o0];
            const float w4[4] = {wv.x, wv.y, wv.z, wv.w};
            float a8[8];
#pragma unroll
            for (int ej = 0; ej < 8; ++ej) a8[ej] = tp[ej];
#pragma unroll
            for (int oi = 0; oi < 4; ++oi)
#pragma unroll
                for (int ej = 0; ej < 8; ++ej)
                    acc[oi][ej] = fmaf(w4[oi], a8[ej], acc[oi][ej]);
        }
    }

    // ---------------- residual + LayerNorm epilogue ----------------
    const float4 bb = *(const float4*)&b2[o0];
    float x[4][8];
#pragma unroll
    for (int ej = 0; ej < 8; ++ej) {
        int v  = vbase + e0 + ej;
        int vc = (v < N) ? v : (N - 1);
        const float4 hv = *(const float4*)&h[(size_t)vc * HD + o0];
        x[0][ej] = acc[0][ej] + bb.x + hv.x;
        x[1][ej] = acc[1][ej] + bb.y + hv.y;
        x[2][ej] = acc[2][ej] + bb.z + hv.z;
        x[3][ej] = acc[3][ej] + bb.w + hv.w;
    }
    float s[8], sq[8];
#pragma unroll
    for (int ej = 0; ej < 8; ++ej) {
        s[ej]  = x[0][ej] + x[1][ej] + x[2][ej] + x[3][ej];
        sq[ej] = x[0][ej]*x[0][ej] + x[1][ej]*x[1][ej]
               + x[2][ej]*x[2][ej] + x[3][ej]*x[3][ej];
    }
#pragma unroll
    for (int m = 1; m <= 16; m <<= 1) {
#pragma unroll
        for (int ej = 0; ej < 8; ++ej) {
            s[ej]  += __shfl_xor(s[ej],  m, 64);
            sq[ej] += __shfl_xor(sq[ej], m, 64);
        }
    }
    const float4 g4  = *(const float4*)&gamma[o0];
    const float4 be4 = *(const float4*)&beta[o0];
#pragma unroll
    for (int ej = 0; ej < 8; ++ej) {
        int v = vbase + e0 + ej;
        if (v < N) {
            const float mean = s[ej] * (1.f / HD);
            const float var  = sq[ej] * (1.f / HD) - mean * mean;
            const float rstd = rsqrtf(var + 1e-5f);
            float4 o4;
            o4.x = (x[0][ej] - mean) * rstd * g4.x + be4.x;
            o4.y = (x[1][ej] - mean) * rstd * g4.y + be4.y;
            o4.z = (x[2][ej] - mean) * rstd * g4.z + be4.z;
            o4.w = (x[3][ej] - mean) * rstd * g4.w + be4.w;
            *(float4*)&out[(size_t)v * HD + o0] = o4;
        }
    }
}

// ---------------------------------------------------------------- launch
extern "C" void kernel_launch(void* const* d_in, const int* in_sizes, int n_in,
                              void* d_out, int out_size, void* d_ws, size_t ws_size,
                              hipStream_t stream)
{
    const float* h     = (const float*)d_in[0];
    const int*   eidx  = (const int*)  d_in[1];
    const float* ea    = (const float*)d_in[2];
    const float* ew1   = (const float*)d_in[3];
    const float* eb1   = (const float*)d_in[4];
    const float* ew2   = (const float*)d_in[5];
    const float* eb2   = (const float*)d_in[6];
    const float* nw1   = (const float*)d_in[7];
    const float* nb1   = (const float*)d_in[8];
    const float* nw2   = (const float*)d_in[9];
    const float* nb2   = (const float*)d_in[10];
    const float* gamma = (const float*)d_in[11];
    const float* beta  = (const float*)d_in[12];
    float* out = (float*)d_out;

    const int N = in_sizes[0] / HD;
    const int E = in_sizes[1] / 2;

    float* agg = (float*)d_ws;          // [N][HD] scratch accumulator
    const long aggn4 = (long)N * HD / 4;

    zero_f32<<<1024, 256, 0, stream>>>((float4*)agg, aggn4);
    edge_msg_kernel<<<(E + TE - 1) / TE, 256, 0, stream>>>(
        h, eidx, ea, ew1, eb1, ew2, eb2, agg, E);
    node_upd_kernel<<<(N + TE - 1) / TE, 256, 0, stream>>>(
        h, agg, nw1, nb1, nw2, nb2, gamma, beta, out, N);
}

// Round 2
// 1112.801 us; speedup vs baseline: 1.2323x; 1.2323x over previous
//
#include <hip/hip_runtime.h>
#include <cstdint>

#define HD 128
#define ED 32
#define BM 128            // edges / nodes per block (output columns)
#define PAD_E 296         // sA row stride (fp16), edge kernel: 288+8
#define PAD_N 264         // sA row stride (fp16), node kernel: 256+8
#define PAD_T 136         // sT row stride (fp16): 128+8

typedef _Float16 f16;
typedef __attribute__((ext_vector_type(4))) _Float16 f16x4;
typedef __attribute__((ext_vector_type(8))) _Float16 f16x8;
typedef __attribute__((ext_vector_type(4))) float    f32x4;

__device__ __forceinline__ f32x4 mfma16(f16x8 a, f16x8 b, f32x4 c) {
    return __builtin_amdgcn_mfma_f32_16x16x32_f16(a, b, c, 0, 0, 0);
}

// ---------------------------------------------------------------- zero ws
__global__ __launch_bounds__(256) void zero_f32(float4* p, long n4) {
    long i = (long)blockIdx.x * blockDim.x + threadIdx.x;
    const long stride = (long)gridDim.x * blockDim.x;
    const float4 z = make_float4(0.f, 0.f, 0.f, 0.f);
    for (; i < n4; i += stride) p[i] = z;
}

// ---------------------------------------------------------------- edges
// Computes out1[hid][edge] = w1^T x m_in^T tiles with MFMA; weights in regs.
// wave wv owns hid rows [32*wv, 32*wv+32), all 128 edges (8 edge-tiles).
__global__ __launch_bounds__(256, 2)
void edge_kernel(const float* __restrict__ h,
                 const int*   __restrict__ eidx,   // [2][E]
                 const float* __restrict__ ea,     // [E][ED]
                 const float* __restrict__ w1,     // [288][HD]
                 const float* __restrict__ b1,     // [HD]
                 const float* __restrict__ w2,     // [HD][HD]
                 const float* __restrict__ b2,     // [HD]
                 float*       __restrict__ agg,    // [N][HD]
                 int E)
{
    __shared__ f16 sA[BM * PAD_E];    // 75776 B; sT aliases the front
    __shared__ int sDst[BM];

    const int t  = threadIdx.x;
    const int l  = t & 63;
    const int wv = t >> 6;            // wave 0..3
    const int li = l & 15;
    const int q  = l >> 4;            // 0..3
    const int ebase = blockIdx.x * BM;

    if (t < BM) sDst[t] = eidx[E + ebase + t];

    // ---- stage sA[edge][0..288) = [h[src] | h[dst] | ea] as fp16 ----
    {
        const int r    = t >> 1;
        const int half = t & 1;
        const int e    = ebase + r;
        const int src  = eidx[e];
        const int dst  = eidx[E + e];
        const float* base0 = h  + (size_t)src * HD;
        const float* base1 = h  + (size_t)dst * HD;
        const float* base2 = ea + (size_t)e * ED;
        f16* row = sA + r * PAD_E;
#pragma unroll
        for (int i = 0; i < 18; ++i) {
            const int c = half * 144 + i * 8;
            const float* p = (c < HD)     ? (base0 + c)
                           : (c < 2 * HD) ? (base1 + (c - HD))
                                          : (base2 + (c - 2 * HD));
            const float4 a0 = *(const float4*)p;
            const float4 a1 = *(const float4*)(p + 4);
            f16x8 v;
            v[0] = (f16)a0.x; v[1] = (f16)a0.y; v[2] = (f16)a0.z; v[3] = (f16)a0.w;
            v[4] = (f16)a1.x; v[5] = (f16)a1.y; v[6] = (f16)a1.z; v[7] = (f16)a1.w;
            *(f16x8*)(row + c) = v;
        }
    }

    // ---- load A1 = w1^T fragments into registers: 2 hid-tiles x 9 k-tiles
    f16x8 A1[2][9];
#pragma unroll
    for (int ht = 0; ht < 2; ++ht) {
#pragma unroll
        for (int kt = 0; kt < 9; ++kt) {
            const float* p = w1 + (size_t)(32 * kt + 8 * q) * HD
                                + (32 * wv + 16 * ht + li);
            f16x8 v;
#pragma unroll
            for (int e2 = 0; e2 < 8; ++e2) v[e2] = (f16)p[(size_t)e2 * HD];
            A1[ht][kt] = v;
        }
    }
    __syncthreads();

    // ---- GEMM1: out1[hid][edge], K = 288 ----
    f32x4 acc[2][8];
#pragma unroll
    for (int i = 0; i < 2; ++i)
#pragma unroll
        for (int j = 0; j < 8; ++j) acc[i][j] = (f32x4){0.f, 0.f, 0.f, 0.f};

#pragma unroll
    for (int kt = 0; kt < 9; ++kt) {
#pragma unroll
        for (int et = 0; et < 8; ++et) {
            const f16x8 bfr = *(const f16x8*)(sA + (16 * et + li) * PAD_E
                                                 + 32 * kt + 8 * q);
            acc[0][et] = mfma16(A1[0][kt], bfr, acc[0][et]);
            acc[1][et] = mfma16(A1[1][kt], bfr, acc[1][et]);
        }
    }
    __syncthreads();   // all waves done reading sA before sT overwrite

    // ---- load A2 = w2^T fragments (overlaps epilogue1) ----
    f16x8 A2[2][4];
#pragma unroll
    for (int ht = 0; ht < 2; ++ht) {
#pragma unroll
        for (int kt = 0; kt < 4; ++kt) {
            const float* p = w2 + (size_t)(32 * kt + 8 * q) * HD
                                + (32 * wv + 16 * ht + li);
            f16x8 v;
#pragma unroll
            for (int e2 = 0; e2 < 8; ++e2) v[e2] = (f16)p[(size_t)e2 * HD];
            A2[ht][kt] = v;
        }
    }

    // ---- epilogue1: +b1, relu, fp16 -> sT[edge][hid] (aliases sA) ----
    f16* sT = sA;
#pragma unroll
    for (int ht = 0; ht < 2; ++ht) {
        const int hidb = 32 * wv + 16 * ht + 4 * q;
        const float4 bb = *(const float4*)(b1 + hidb);
#pragma unroll
        for (int et = 0; et < 8; ++et) {
            const f32x4 v = acc[ht][et];
            float x0 = v[0] + bb.x, x1 = v[1] + bb.y,
                  x2 = v[2] + bb.z, x3 = v[3] + bb.w;
            x0 = x0 > 0.f ? x0 : 0.f;  x1 = x1 > 0.f ? x1 : 0.f;
            x2 = x2 > 0.f ? x2 : 0.f;  x3 = x3 > 0.f ? x3 : 0.f;
            f16x4 o; o[0] = (f16)x0; o[1] = (f16)x1; o[2] = (f16)x2; o[3] = (f16)x3;
            *(f16x4*)(sT + (16 * et + li) * PAD_T + hidb) = o;
        }
    }
    __syncthreads();

    // ---- GEMM2: out2[hid2][edge], K = 128 ----
    f32x4 acc2[2][8];
#pragma unroll
    for (int i = 0; i < 2; ++i)
#pragma unroll
        for (int j = 0; j < 8; ++j) acc2[i][j] = (f32x4){0.f, 0.f, 0.f, 0.f};

#pragma unroll
    for (int kt = 0; kt < 4; ++kt) {
#pragma unroll
        for (int et = 0; et < 8; ++et) {
            const f16x8 bfr = *(const f16x8*)(sT + (16 * et + li) * PAD_T
                                                 + 32 * kt + 8 * q);
            acc2[0][et] = mfma16(A2[0][kt], bfr, acc2[0][et]);
            acc2[1][et] = mfma16(A2[1][kt], bfr, acc2[1][et]);
        }
    }

    // ---- epilogue2: +b2, atomic scatter into agg ----
#pragma unroll
    for (int ht = 0; ht < 2; ++ht) {
        const int hidb = 32 * wv + 16 * ht + 4 * q;
        const float4 bb = *(const float4*)(b2 + hidb);
#pragma unroll
        for (int et = 0; et < 8; ++et) {
            const int edge = 16 * et + li;
            float* p = agg + (size_t)sDst[edge] * HD + hidb;
            const f32x4 v = acc2[ht][et];
            atomicAdd(p + 0, v[0] + bb.x);
            atomicAdd(p + 1, v[1] + bb.y);
            atomicAdd(p + 2, v[2] + bb.z);
            atomicAdd(p + 3, v[3] + bb.w);
        }
    }
}

// ---------------------------------------------------------------- nodes
__global__ __launch_bounds__(256, 1)
void node_kernel(const float* __restrict__ h,
                 const float* __restrict__ agg,
                 const float* __restrict__ w1,    // [256][HD]
                 const float* __restrict__ b1,
                 const float* __restrict__ w2,    // [HD][HD]
                 const float* __restrict__ b2,
                 const float* __restrict__ gamma,
                 const float* __restrict__ beta,
                 float*       __restrict__ out,
                 int N)
{
    __shared__ f16   sA[BM * PAD_N];   // 67584 B; sX (f32 [128][132]) aliases
    __shared__ f16   sT[BM * PAD_T];   // 34816 B
    __shared__ float sMV[2 * BM];

    const int t  = threadIdx.x;
    const int l  = t & 63;
    const int wv = t >> 6;
    const int li = l & 15;
    const int q  = l >> 4;
    const int nbase = blockIdx.x * BM;

    // ---- stage sA[node][0..256) = [h | agg] as fp16 ----
    {
        const int r    = t >> 1;
        const int half = t & 1;
        const int node = min(nbase + r, N - 1);
        const float* base0 = h   + (size_t)node * HD;
        const float* base1 = agg + (size_t)node * HD;
        f16* row = sA + r * PAD_N;
#pragma unroll
        for (int i = 0; i < 16; ++i) {
            const int c = half * 128 + i * 8;
            const float* p = (c < HD) ? (base0 + c) : (base1 + (c - HD));
            const float4 a0 = *(const float4*)p;
            const float4 a1 = *(const float4*)(p + 4);
            f16x8 v;
            v[0] = (f16)a0.x; v[1] = (f16)a0.y; v[2] = (f16)a0.z; v[3] = (f16)a0.w;
            v[4] = (f16)a1.x; v[5] = (f16)a1.y; v[6] = (f16)a1.z; v[7] = (f16)a1.w;
            *(f16x8*)(row + c) = v;
        }
    }

    // ---- A1 = nw1^T fragments: 2 hid-tiles x 8 k-tiles ----
    f16x8 A1[2][8];
#pragma unroll
    for (int ht = 0; ht < 2; ++ht) {
#pragma unroll
        for (int kt = 0; kt < 8; ++kt) {
            const float* p = w1 + (size_t)(32 * kt + 8 * q) * HD
                                + (32 * wv + 16 * ht + li);
            f16x8 v;
#pragma unroll
            for (int e2 = 0; e2 < 8; ++e2) v[e2] = (f16)p[(size_t)e2 * HD];
            A1[ht][kt] = v;
        }
    }
    __syncthreads();

    // ---- GEMM1: K = 256 ----
    f32x4 acc[2][8];
#pragma unroll
    for (int i = 0; i < 2; ++i)
#pragma unroll
        for (int j = 0; j < 8; ++j) acc[i][j] = (f32x4){0.f, 0.f, 0.f, 0.f};

#pragma unroll
    for (int kt = 0; kt < 8; ++kt) {
#pragma unroll
        for (int et = 0; et < 8; ++et) {
            const f16x8 bfr = *(const f16x8*)(sA + (16 * et + li) * PAD_N
                                                 + 32 * kt + 8 * q);
            acc[0][et] = mfma16(A1[0][kt], bfr, acc[0][et]);
            acc[1][et] = mfma16(A1[1][kt], bfr, acc[1][et]);
        }
    }
    __syncthreads();

    // ---- A2 = nw2^T fragments ----
    f16x8 A2[2][4];
#pragma unroll
    for (int ht = 0; ht < 2; ++ht) {
#pragma unroll
        for (int kt = 0; kt < 4; ++kt) {
            const float* p = w2 + (size_t)(32 * kt + 8 * q) * HD
                                + (32 * wv + 16 * ht + li);
            f16x8 v;
#pragma unroll
            for (int e2 = 0; e2 < 8; ++e2) v[e2] = (f16)p[(size_t)e2 * HD];
            A2[ht][kt] = v;
        }
    }

    // ---- epilogue1: +b1, relu -> sT[node][hid] ----
#pragma unroll
    for (int ht = 0; ht < 2; ++ht) {
        const int hidb = 32 * wv + 16 * ht + 4 * q;
        const float4 bb = *(const float4*)(b1 + hidb);
#pragma unroll
        for (int et = 0; et < 8; ++et) {
            const f32x4 v = acc[ht][et];
            float x0 = v[0] + bb.x, x1 = v[1] + bb.y,
                  x2 = v[2] + bb.z, x3 = v[3] + bb.w;
            x0 = x0 > 0.f ? x0 : 0.f;  x1 = x1 > 0.f ? x1 : 0.f;
            x2 = x2 > 0.f ? x2 : 0.f;  x3 = x3 > 0.f ? x3 : 0.f;
            f16x4 o; o[0] = (f16)x0; o[1] = (f16)x1; o[2] = (f16)x2; o[3] = (f16)x3;
            *(f16x4*)(sT + (16 * et + li) * PAD_T + hidb) = o;
        }
    }
    __syncthreads();

    // ---- GEMM2: K = 128 ----
    f32x4 acc2[2][8];
#pragma unroll
    for (int i = 0; i < 2; ++i)
#pragma unroll
        for (int j = 0; j < 8; ++j) acc2[i][j] = (f32x4){0.f, 0.f, 0.f, 0.f};

#pragma unroll
    for (int kt = 0; kt < 4; ++kt) {
#pragma unroll
        for (int et = 0; et < 8; ++et) {
            const f16x8 bfr = *(const f16x8*)(sT + (16 * et + li) * PAD_T
                                                 + 32 * kt + 8 * q);
            acc2[0][et] = mfma16(A2[0][kt], bfr, acc2[0][et]);
            acc2[1][et] = mfma16(A2[1][kt], bfr, acc2[1][et]);
        }
    }
    __syncthreads();   // sA (aliased by sX) fully dead

    // ---- epilogue2: x = upd + b2 + h  -> sX[node][hid] (f32, aliases sA) ----
    float* sX = (float*)sA;            // stride 132 f32
#pragma unroll
    for (int ht = 0; ht < 2; ++ht) {
        const int hidb = 32 * wv + 16 * ht + 4 * q;
        const float4 bb = *(const float4*)(b2 + hidb);
#pragma unroll
        for (int et = 0; et < 8; ++et) {
            const int node = 16 * et + li;
            const int nc   = min(nbase + node, N - 1);
            const float4 hv = *(const float4*)(h + (size_t)nc * HD + hidb);
            const f32x4 v = acc2[ht][et];
            f32x4 x;
            x[0] = v[0] + bb.x + hv.x;
            x[1] = v[1] + bb.y + hv.y;
            x[2] = v[2] + bb.z + hv.z;
            x[3] = v[3] + bb.w + hv.w;
            *(f32x4*)(sX + (16 * et + li) * 132 + hidb) = x;
        }
    }
    __syncthreads();

    // ---- LayerNorm pass A: per-node mean/rstd ----
    {
        const int node  = t >> 1;
        const int half2 = t & 1;
        const float* px = sX + node * 132 + half2 * 64;
        float s = 0.f, sq = 0.f;
#pragma unroll
        for (int i = 0; i < 16; ++i) {
            const float4 v = *(const float4*)(px + i * 4);
            s  += v.x + v.y + v.z + v.w;
            sq += v.x * v.x + v.y * v.y + v.z * v.z + v.w * v.w;
        }
        s  += __shfl_xor(s, 1);
        sq += __shfl_xor(sq, 1);
        if (!half2) {
            const float mean = s * (1.f / HD);
            const float var  = sq * (1.f / HD) - mean * mean;
            sMV[node]      = mean;
            sMV[BM + node] = rsqrtf(var + 1e-5f);
        }
    }
    __syncthreads();

    // ---- LayerNorm pass B: normalize + coalesced store ----
#pragma unroll
    for (int i = 0; i < 16; ++i) {
        const int idx  = t + i * 256;
        const int node = idx >> 5;
        const int c4   = (idx & 31) * 4;
        if (nbase + node < N) {
            const float4 xv = *(const float4*)(sX + node * 132 + c4);
            const float4 g4 = *(const float4*)(gamma + c4);
            const float4 b4 = *(const float4*)(beta + c4);
            const float mean = sMV[node];
            const float rstd = sMV[BM + node];
            float4 o;
            o.x = (xv.x - mean) * rstd * g4.x + b4.x;
            o.y = (xv.y - mean) * rstd * g4.y + b4.y;
            o.z = (xv.z - mean) * rstd * g4.z + b4.z;
            o.w = (xv.w - mean) * rstd * g4.w + b4.w;
            *(float4*)(out + (size_t)(nbase + node) * HD + c4) = o;
        }
    }
}

// ---------------------------------------------------------------- launch
extern "C" void kernel_launch(void* const* d_in, const int* in_sizes, int n_in,
                              void* d_out, int out_size, void* d_ws, size_t ws_size,
                              hipStream_t stream)
{
    const float* h     = (const float*)d_in[0];
    const int*   eidx  = (const int*)  d_in[1];
    const float* ea    = (const float*)d_in[2];
    const float* ew1   = (const float*)d_in[3];
    const float* eb1   = (const float*)d_in[4];
    const float* ew2   = (const float*)d_in[5];
    const float* eb2   = (const float*)d_in[6];
    const float* nw1   = (const float*)d_in[7];
    const float* nb1   = (const float*)d_in[8];
    const float* nw2   = (const float*)d_in[9];
    const float* nb2   = (const float*)d_in[10];
    const float* gamma = (const float*)d_in[11];
    const float* beta  = (const float*)d_in[12];
    float* out = (float*)d_out;

    const int N = in_sizes[0] / HD;
    const int E = in_sizes[1] / 2;

    float* agg = (float*)d_ws;
    const long aggn4 = (long)N * HD / 4;

    zero_f32<<<1024, 256, 0, stream>>>((float4*)agg, aggn4);
    edge_kernel<<<(E + BM - 1) / BM, 256, 0, stream>>>(
        h, eidx, ea, ew1, eb1, ew2, eb2, agg, E);
    node_kernel<<<(N + BM - 1) / BM, 256, 0, stream>>>(
        h, agg, nw1, nb1, nw2, nb2, gamma, beta, out, N);
}

// Round 3
// 365.501 us; speedup vs baseline: 3.7518x; 3.0446x over previous
//
#include <hip/hip_runtime.h>
#include <cstdint>

#define HD 128
#define ED 32
#define BM 128            // edges / nodes per block (output columns)
#define PAD_E 296         // sA row stride (fp16), edge kernel: 288+8
#define PAD_N 264         // sA row stride (fp16), node kernel: 256+8
#define PAD_T 136         // sT row stride (fp16): 128+8

typedef _Float16 f16;
typedef __attribute__((ext_vector_type(2))) _Float16 f16x2;
typedef __attribute__((ext_vector_type(4))) _Float16 f16x4;
typedef __attribute__((ext_vector_type(8))) _Float16 f16x8;
typedef __attribute__((ext_vector_type(4))) float    f32x4;

__device__ __forceinline__ f32x4 mfma16(f16x8 a, f16x8 b, f32x4 c) {
    return __builtin_amdgcn_mfma_f32_16x16x32_f16(a, b, c, 0, 0, 0);
}

// ---------------------------------------------------------------- zero
__global__ __launch_bounds__(256) void zero_f32(float4* p, long n4) {
    long i = (long)blockIdx.x * blockDim.x + threadIdx.x;
    const long stride = (long)gridDim.x * blockDim.x;
    const float4 z = make_float4(0.f, 0.f, 0.f, 0.f);
    for (; i < n4; i += stride) p[i] = z;
}
__global__ __launch_bounds__(256) void zero_i32(int* p, int n) {
    int i = blockIdx.x * blockDim.x + threadIdx.x;
    if (i < n) p[i] = 0;
}

// ---------------------------------------------------------------- CSR build
__global__ __launch_bounds__(256)
void hist_kernel(const int* __restrict__ eidx, int* __restrict__ rank,
                 int* __restrict__ cnt, int E) {
    int e = blockIdx.x * 256 + threadIdx.x;
    if (e < E) rank[e] = atomicAdd(&cnt[eidx[E + e]], 1);
}

// single-block exclusive scan: rs[0..N] from cnt[0..N-1]
__global__ __launch_bounds__(1024)
void scan_kernel(const int* __restrict__ cnt, int* __restrict__ rs, int N) {
    __shared__ int wsum[16];
    __shared__ int s_carry;
    const int t = threadIdx.x, lane = t & 63, wid = t >> 6;
    if (t == 0) s_carry = 0;
    __syncthreads();
    for (int base = 0; base < N; base += 1024) {
        const int i = base + t;
        const int v = (i < N) ? cnt[i] : 0;
        int incl = v;
#pragma unroll
        for (int off = 1; off < 64; off <<= 1) {
            int u = __shfl_up(incl, off, 64);
            if (lane >= off) incl += u;
        }
        if (lane == 63) wsum[wid] = incl;
        __syncthreads();
        if (t == 0) {
            int s = 0;
#pragma unroll
            for (int w = 0; w < 16; ++w) { int x = wsum[w]; wsum[w] = s; s += x; }
        }
        __syncthreads();
        const int carry = s_carry;
        if (i < N) rs[i] = carry + wsum[wid] + incl - v;
        __syncthreads();
        if (t == 1023) s_carry = carry + wsum[15] + incl;
        __syncthreads();
    }
    if (threadIdx.x == 0) rs[N] = s_carry;
}

__global__ __launch_bounds__(256)
void pos_kernel(const int* __restrict__ eidx, const int* __restrict__ rs,
                int* __restrict__ pos, int E) {
    int e = blockIdx.x * 256 + threadIdx.x;
    if (e < E) pos[e] = rs[eidx[E + e]] + pos[e];
}

// ---------------------------------------------------------------- edges
// MODE 0: atomic fp32 scatter into agg.  MODE 1: store f16 row at m[pos[e]].
template <int MODE>
__global__ __launch_bounds__(256, 2)
void edge_kernel(const float* __restrict__ h,
                 const int*   __restrict__ eidx,   // [2][E]
                 const float* __restrict__ ea,     // [E][ED]
                 const float* __restrict__ w1,     // [288][HD]
                 const float* __restrict__ b1,
                 const float* __restrict__ w2,     // [HD][HD]
                 const float* __restrict__ b2,
                 float*       __restrict__ aggm,   // agg [N][HD] or m [E][HD] f16
                 const int*   __restrict__ pos,    // MODE1: CSR slot per edge
                 int E)
{
    __shared__ f16 sA[BM * PAD_E];    // 75776 B; sT aliases the front
    __shared__ int sIdx[BM];

    const int t  = threadIdx.x;
    const int l  = t & 63;
    const int wv = t >> 6;
    const int li = l & 15;
    const int q  = l >> 4;
    const int ebase = blockIdx.x * BM;

    if (t < BM) {
        int e  = ebase + t;
        int ec = (e < E) ? e : (E - 1);
        sIdx[t] = (MODE == 0) ? eidx[E + ec] : pos[ec];
    }

    // ---- stage sA[edge][0..288) = [h[src] | h[dst] | ea] as fp16 ----
    {
        const int r    = t >> 1;
        const int half = t & 1;
        const int e    = ebase + r;
        const int ec   = (e < E) ? e : (E - 1);
        const int src  = eidx[ec];
        const int dst  = eidx[E + ec];
        const float* base0 = h  + (size_t)src * HD;
        const float* base1 = h  + (size_t)dst * HD;
        const float* base2 = ea + (size_t)ec * ED;
        f16* row = sA + r * PAD_E;
#pragma unroll
        for (int i = 0; i < 18; ++i) {
            const int c = half * 144 + i * 8;
            const float* p = (c < HD)     ? (base0 + c)
                           : (c < 2 * HD) ? (base1 + (c - HD))
                                          : (base2 + (c - 2 * HD));
            const float4 a0 = *(const float4*)p;
            const float4 a1 = *(const float4*)(p + 4);
            f16x8 v;
            v[0] = (f16)a0.x; v[1] = (f16)a0.y; v[2] = (f16)a0.z; v[3] = (f16)a0.w;
            v[4] = (f16)a1.x; v[5] = (f16)a1.y; v[6] = (f16)a1.z; v[7] = (f16)a1.w;
            *(f16x8*)(row + c) = v;
        }
    }

    // ---- A1 = w1^T fragments in registers: 2 hid-tiles x 9 k-tiles ----
    f16x8 A1[2][9];
#pragma unroll
    for (int ht = 0; ht < 2; ++ht) {
#pragma unroll
        for (int kt = 0; kt < 9; ++kt) {
            const float* p = w1 + (size_t)(32 * kt + 8 * q) * HD
                                + (32 * wv + 16 * ht + li);
            f16x8 v;
#pragma unroll
            for (int e2 = 0; e2 < 8; ++e2) v[e2] = (f16)p[(size_t)e2 * HD];
            A1[ht][kt] = v;
        }
    }
    __syncthreads();

    // ---- GEMM1: out1[hid][edge], K = 288 ----
    f32x4 acc[2][8];
#pragma unroll
    for (int i = 0; i < 2; ++i)
#pragma unroll
        for (int j = 0; j < 8; ++j) acc[i][j] = (f32x4){0.f, 0.f, 0.f, 0.f};

#pragma unroll
    for (int kt = 0; kt < 9; ++kt) {
#pragma unroll
        for (int et = 0; et < 8; ++et) {
            const f16x8 bfr = *(const f16x8*)(sA + (16 * et + li) * PAD_E
                                                 + 32 * kt + 8 * q);
            acc[0][et] = mfma16(A1[0][kt], bfr, acc[0][et]);
            acc[1][et] = mfma16(A1[1][kt], bfr, acc[1][et]);
        }
    }
    __syncthreads();   // all waves done reading sA before sT overwrite

    // ---- A2 = w2^T fragments ----
    f16x8 A2[2][4];
#pragma unroll
    for (int ht = 0; ht < 2; ++ht) {
#pragma unroll
        for (int kt = 0; kt < 4; ++kt) {
            const float* p = w2 + (size_t)(32 * kt + 8 * q) * HD
                                + (32 * wv + 16 * ht + li);
            f16x8 v;
#pragma unroll
            for (int e2 = 0; e2 < 8; ++e2) v[e2] = (f16)p[(size_t)e2 * HD];
            A2[ht][kt] = v;
        }
    }

    // ---- epilogue1: +b1, relu, fp16 -> sT[edge][hid] (aliases sA) ----
    f16* sT = sA;
#pragma unroll
    for (int ht = 0; ht < 2; ++ht) {
        const int hidb = 32 * wv + 16 * ht + 4 * q;
        const float4 bb = *(const float4*)(b1 + hidb);
#pragma unroll
        for (int et = 0; et < 8; ++et) {
            const f32x4 v = acc[ht][et];
            float x0 = v[0] + bb.x, x1 = v[1] + bb.y,
                  x2 = v[2] + bb.z, x3 = v[3] + bb.w;
            x0 = x0 > 0.f ? x0 : 0.f;  x1 = x1 > 0.f ? x1 : 0.f;
            x2 = x2 > 0.f ? x2 : 0.f;  x3 = x3 > 0.f ? x3 : 0.f;
            f16x4 o; o[0] = (f16)x0; o[1] = (f16)x1; o[2] = (f16)x2; o[3] = (f16)x3;
            *(f16x4*)(sT + (16 * et + li) * PAD_T + hidb) = o;
        }
    }
    __syncthreads();

    // ---- GEMM2: out2[hid2][edge], K = 128 ----
    f32x4 acc2[2][8];
#pragma unroll
    for (int i = 0; i < 2; ++i)
#pragma unroll
        for (int j = 0; j < 8; ++j) acc2[i][j] = (f32x4){0.f, 0.f, 0.f, 0.f};

#pragma unroll
    for (int kt = 0; kt < 4; ++kt) {
#pragma unroll
        for (int et = 0; et < 8; ++et) {
            const f16x8 bfr = *(const f16x8*)(sT + (16 * et + li) * PAD_T
                                                 + 32 * kt + 8 * q);
            acc2[0][et] = mfma16(A2[0][kt], bfr, acc2[0][et]);
            acc2[1][et] = mfma16(A2[1][kt], bfr, acc2[1][et]);
        }
    }

    if (MODE == 0) {
        // ---- +b2, atomic scatter into agg ----
#pragma unroll
        for (int ht = 0; ht < 2; ++ht) {
            const int hidb = 32 * wv + 16 * ht + 4 * q;
            const float4 bb = *(const float4*)(b2 + hidb);
#pragma unroll
            for (int et = 0; et < 8; ++et) {
                const int edge = 16 * et + li;
                if (ebase + edge < E) {
                    float* p = aggm + (size_t)sIdx[edge] * HD + hidb;
                    const f32x4 v = acc2[ht][et];
                    atomicAdd(p + 0, v[0] + bb.x);
                    atomicAdd(p + 1, v[1] + bb.y);
                    atomicAdd(p + 2, v[2] + bb.z);
                    atomicAdd(p + 3, v[3] + bb.w);
                }
            }
        }
    } else {
        // ---- +b2 -> f16 tile in LDS (reuse sT area), then row stores ----
        __syncthreads();   // GEMM2 done reading sT
#pragma unroll
        for (int ht = 0; ht < 2; ++ht) {
            const int hidb = 32 * wv + 16 * ht + 4 * q;
            const float4 bb = *(const float4*)(b2 + hidb);
#pragma unroll
            for (int et = 0; et < 8; ++et) {
                const f32x4 v = acc2[ht][et];
                f16x4 o;
                o[0] = (f16)(v[0] + bb.x); o[1] = (f16)(v[1] + bb.y);
                o[2] = (f16)(v[2] + bb.z); o[3] = (f16)(v[3] + bb.w);
                *(f16x4*)(sT + (16 * et + li) * PAD_T + hidb) = o;
            }
        }
        __syncthreads();
        f16* mb = (f16*)aggm;
#pragma unroll
        for (int i = 0; i < 8; ++i) {
            const int idx = t + i * 256;      // 0..2047
            const int row = idx >> 4;
            const int c8  = (idx & 15) * 8;
            if (ebase + row < E) {
                const f16x8 v = *(const f16x8*)(sT + row * PAD_T + c8);
                *(f16x8*)(mb + (size_t)sIdx[row] * HD + c8) = v;
            }
        }
    }
}

// ---------------------------------------------------------------- gather
// one wave per node: sum contiguous CSR segment of f16 message rows -> agg f32
__global__ __launch_bounds__(256)
void gather_kernel(const f16* __restrict__ m, const int* __restrict__ rs,
                   float* __restrict__ agg, int N)
{
    const int n = blockIdx.x * 4 + (threadIdx.x >> 6);
    if (n >= N) return;
    const int lane = threadIdx.x & 63;
    const int s = rs[n], e = rs[n + 1];
    const f16* base = m + (size_t)s * HD + lane * 2;
    const int cnt = e - s;
    float a0 = 0.f, b0 = 0.f, a1 = 0.f, b1 = 0.f;
    int j = 0;
    for (; j + 2 <= cnt; j += 2) {
        const f16x2 u = *(const f16x2*)(base + (size_t)j * HD);
        const f16x2 v = *(const f16x2*)(base + (size_t)(j + 1) * HD);
        a0 += (float)u[0]; b0 += (float)u[1];
        a1 += (float)v[0]; b1 += (float)v[1];
    }
    if (j < cnt) {
        const f16x2 u = *(const f16x2*)(base + (size_t)j * HD);
        a0 += (float)u[0]; b0 += (float)u[1];
    }
    float2 r; r.x = a0 + a1; r.y = b0 + b1;
    *(float2*)(agg + (size_t)n * HD + lane * 2) = r;
}

// ---------------------------------------------------------------- nodes
__global__ __launch_bounds__(256, 1)
void node_kernel(const float* __restrict__ h,
                 const float* __restrict__ agg,
                 const float* __restrict__ w1,    // [256][HD]
                 const float* __restrict__ b1,
                 const float* __restrict__ w2,    // [HD][HD]
                 const float* __restrict__ b2,
                 const float* __restrict__ gamma,
                 const float* __restrict__ beta,
                 float*       __restrict__ out,
                 int N)
{
    __shared__ f16   sA[BM * PAD_N];   // sX (f32 [128][132]) aliases
    __shared__ f16   sT[BM * PAD_T];
    __shared__ float sMV[2 * BM];

    const int t  = threadIdx.x;
    const int l  = t & 63;
    const int wv = t >> 6;
    const int li = l & 15;
    const int q  = l >> 4;
    const int nbase = blockIdx.x * BM;

    // ---- stage sA[node][0..256) = [h | agg] as fp16 ----
    {
        const int r    = t >> 1;
        const int half = t & 1;
        const int node = min(nbase + r, N - 1);
        const float* base0 = h   + (size_t)node * HD;
        const float* base1 = agg + (size_t)node * HD;
        f16* row = sA + r * PAD_N;
#pragma unroll
        for (int i = 0; i < 16; ++i) {
            const int c = half * 128 + i * 8;
            const float* p = (c < HD) ? (base0 + c) : (base1 + (c - HD));
            const float4 a0 = *(const float4*)p;
            const float4 a1 = *(const float4*)(p + 4);
            f16x8 v;
            v[0] = (f16)a0.x; v[1] = (f16)a0.y; v[2] = (f16)a0.z; v[3] = (f16)a0.w;
            v[4] = (f16)a1.x; v[5] = (f16)a1.y; v[6] = (f16)a1.z; v[7] = (f16)a1.w;
            *(f16x8*)(row + c) = v;
        }
    }

    f16x8 A1[2][8];
#pragma unroll
    for (int ht = 0; ht < 2; ++ht) {
#pragma unroll
        for (int kt = 0; kt < 8; ++kt) {
            const float* p = w1 + (size_t)(32 * kt + 8 * q) * HD
                                + (32 * wv + 16 * ht + li);
            f16x8 v;
#pragma unroll
            for (int e2 = 0; e2 < 8; ++e2) v[e2] = (f16)p[(size_t)e2 * HD];
            A1[ht][kt] = v;
        }
    }
    __syncthreads();

    f32x4 acc[2][8];
#pragma unroll
    for (int i = 0; i < 2; ++i)
#pragma unroll
        for (int j = 0; j < 8; ++j) acc[i][j] = (f32x4){0.f, 0.f, 0.f, 0.f};

#pragma unroll
    for (int kt = 0; kt < 8; ++kt) {
#pragma unroll
        for (int et = 0; et < 8; ++et) {
            const f16x8 bfr = *(const f16x8*)(sA + (16 * et + li) * PAD_N
                                                 + 32 * kt + 8 * q);
            acc[0][et] = mfma16(A1[0][kt], bfr, acc[0][et]);
            acc[1][et] = mfma16(A1[1][kt], bfr, acc[1][et]);
        }
    }
    __syncthreads();

    f16x8 A2[2][4];
#pragma unroll
    for (int ht = 0; ht < 2; ++ht) {
#pragma unroll
        for (int kt = 0; kt < 4; ++kt) {
            const float* p = w2 + (size_t)(32 * kt + 8 * q) * HD
                                + (32 * wv + 16 * ht + li);
            f16x8 v;
#pragma unroll
            for (int e2 = 0; e2 < 8; ++e2) v[e2] = (f16)p[(size_t)e2 * HD];
            A2[ht][kt] = v;
        }
    }

#pragma unroll
    for (int ht = 0; ht < 2; ++ht) {
        const int hidb = 32 * wv + 16 * ht + 4 * q;
        const float4 bb = *(const float4*)(b1 + hidb);
#pragma unroll
        for (int et = 0; et < 8; ++et) {
            const f32x4 v = acc[ht][et];
            float x0 = v[0] + bb.x, x1 = v[1] + bb.y,
                  x2 = v[2] + bb.z, x3 = v[3] + bb.w;
            x0 = x0 > 0.f ? x0 : 0.f;  x1 = x1 > 0.f ? x1 : 0.f;
            x2 = x2 > 0.f ? x2 : 0.f;  x3 = x3 > 0.f ? x3 : 0.f;
            f16x4 o; o[0] = (f16)x0; o[1] = (f16)x1; o[2] = (f16)x2; o[3] = (f16)x3;
            *(f16x4*)(sT + (16 * et + li) * PAD_T + hidb) = o;
        }
    }
    __syncthreads();

    f32x4 acc2[2][8];
#pragma unroll
    for (int i = 0; i < 2; ++i)
#pragma unroll
        for (int j = 0; j < 8; ++j) acc2[i][j] = (f32x4){0.f, 0.f, 0.f, 0.f};

#pragma unroll
    for (int kt = 0; kt < 4; ++kt) {
#pragma unroll
        for (int et = 0; et < 8; ++et) {
            const f16x8 bfr = *(const f16x8*)(sT + (16 * et + li) * PAD_T
                                                 + 32 * kt + 8 * q);
            acc2[0][et] = mfma16(A2[0][kt], bfr, acc2[0][et]);
            acc2[1][et] = mfma16(A2[1][kt], bfr, acc2[1][et]);
        }
    }
    __syncthreads();   // sA (aliased by sX) fully dead

    float* sX = (float*)sA;            // stride 132 f32
#pragma unroll
    for (int ht = 0; ht < 2; ++ht) {
        const int hidb = 32 * wv + 16 * ht + 4 * q;
        const float4 bb = *(const float4*)(b2 + hidb);
#pragma unroll
        for (int et = 0; et < 8; ++et) {
            const int node = 16 * et + li;
            const int nc   = min(nbase + node, N - 1);
            const float4 hv = *(const float4*)(h + (size_t)nc * HD + hidb);
            const f32x4 v = acc2[ht][et];
            f32x4 x;
            x[0] = v[0] + bb.x + hv.x;
            x[1] = v[1] + bb.y + hv.y;
            x[2] = v[2] + bb.z + hv.z;
            x[3] = v[3] + bb.w + hv.w;
            *(f32x4*)(sX + (16 * et + li) * 132 + hidb) = x;
        }
    }
    __syncthreads();

    {
        const int node  = t >> 1;
        const int half2 = t & 1;
        const float* px = sX + node * 132 + half2 * 64;
        float s = 0.f, sq = 0.f;
#pragma unroll
        for (int i = 0; i < 16; ++i) {
            const float4 v = *(const float4*)(px + i * 4);
            s  += v.x + v.y + v.z + v.w;
            sq += v.x * v.x + v.y * v.y + v.z * v.z + v.w * v.w;
        }
        s  += __shfl_xor(s, 1);
        sq += __shfl_xor(sq, 1);
        if (!half2) {
            const float mean = s * (1.f / HD);
            const float var  = sq * (1.f / HD) - mean * mean;
            sMV[node]      = mean;
            sMV[BM + node] = rsqrtf(var + 1e-5f);
        }
    }
    __syncthreads();

#pragma unroll
    for (int i = 0; i < 16; ++i) {
        const int idx  = t + i * 256;
        const int node = idx >> 5;
        const int c4   = (idx & 31) * 4;
        if (nbase + node < N) {
            const float4 xv = *(const float4*)(sX + node * 132 + c4);
            const float4 g4 = *(const float4*)(gamma + c4);
            const float4 b4 = *(const float4*)(beta + c4);
            const float mean = sMV[node];
            const float rstd = sMV[BM + node];
            float4 o;
            o.x = (xv.x - mean) * rstd * g4.x + b4.x;
            o.y = (xv.y - mean) * rstd * g4.y + b4.y;
            o.z = (xv.z - mean) * rstd * g4.z + b4.z;
            o.w = (xv.w - mean) * rstd * g4.w + b4.w;
            *(float4*)(out + (size_t)(nbase + node) * HD + c4) = o;
        }
    }
}

// ---------------------------------------------------------------- launch
extern "C" void kernel_launch(void* const* d_in, const int* in_sizes, int n_in,
                              void* d_out, int out_size, void* d_ws, size_t ws_size,
                              hipStream_t stream)
{
    const float* h     = (const float*)d_in[0];
    const int*   eidx  = (const int*)  d_in[1];
    const float* ea    = (const float*)d_in[2];
    const float* ew1   = (const float*)d_in[3];
    const float* eb1   = (const float*)d_in[4];
    const float* ew2   = (const float*)d_in[5];
    const float* eb2   = (const float*)d_in[6];
    const float* nw1   = (const float*)d_in[7];
    const float* nb1   = (const float*)d_in[8];
    const float* nw2   = (const float*)d_in[9];
    const float* nb2   = (const float*)d_in[10];
    const float* gamma = (const float*)d_in[11];
    const float* beta  = (const float*)d_in[12];
    float* out = (float*)d_out;

    const int N = in_sizes[0] / HD;
    const int E = in_sizes[1] / 2;

    // workspace layout (256B aligned)
    size_t off = 0;
    auto alloc = [&](size_t bytes) {
        size_t o = off; off += (bytes + 255) & ~(size_t)255; return o;
    };
    const size_t o_m   = alloc((size_t)E * HD * sizeof(f16));
    const size_t o_agg = alloc((size_t)N * HD * sizeof(float));
    const size_t o_pos = alloc((size_t)E * sizeof(int));
    const size_t o_rs  = alloc((size_t)(N + 1) * sizeof(int));
    const size_t o_cnt = alloc((size_t)N * sizeof(int));
    const bool csr = (off <= ws_size);
    char* ws = (char*)d_ws;

    if (csr) {
        f16*   mb  = (f16*)(ws + o_m);
        float* agg = (float*)(ws + o_agg);
        int*   pos = (int*)(ws + o_pos);
        int*   rs  = (int*)(ws + o_rs);
        int*   cnt = (int*)(ws + o_cnt);

        zero_i32<<<(N + 255) / 256, 256, 0, stream>>>(cnt, N);
        hist_kernel<<<(E + 255) / 256, 256, 0, stream>>>(eidx, pos, cnt, E);
        scan_kernel<<<1, 1024, 0, stream>>>(cnt, rs, N);
        pos_kernel<<<(E + 255) / 256, 256, 0, stream>>>(eidx, rs, pos, E);
        edge_kernel<1><<<(E + BM - 1) / BM, 256, 0, stream>>>(
            h, eidx, ea, ew1, eb1, ew2, eb2, (float*)mb, pos, E);
        gather_kernel<<<(N + 3) / 4, 256, 0, stream>>>(mb, rs, agg, N);
        node_kernel<<<(N + BM - 1) / BM, 256, 0, stream>>>(
            h, agg, nw1, nb1, nw2, nb2, gamma, beta, out, N);
    } else {
        // fallback: atomic scatter path (round-2 behavior)
        float* agg = (float*)ws;
        zero_f32<<<1024, 256, 0, stream>>>((float4*)agg, (long)N * HD / 4);
        edge_kernel<0><<<(E + BM - 1) / BM, 256, 0, stream>>>(
            h, eidx, ea, ew1, eb1, ew2, eb2, agg, nullptr, E);
        node_kernel<<<(N + BM - 1) / BM, 256, 0, stream>>>(
            h, agg, nw1, nb1, nw2, nb2, gamma, beta, out, N);
    }
}

// Round 6
// 327.006 us; speedup vs baseline: 4.1935x; 1.1177x over previous
//
#include <hip/hip_runtime.h>
#include <cstdint>

#define HD 128
#define ED 32
#define BME 64            // edges per block (edge kernel)
#define BMN 128           // nodes per block (node kernel)
#define PAD_E 296         // sA row stride f16, edge: 288+8  (592 B = 37*16)
#define PAD_N 264         // sA row stride f16, node: 256+8  (528 B = 33*16)
#define PAD_T 136         // sT row stride f16: 128+8        (272 B = 17*16)

typedef _Float16 f16;
typedef __attribute__((ext_vector_type(2))) _Float16 f16x2;
typedef __attribute__((ext_vector_type(4))) _Float16 f16x4;
typedef __attribute__((ext_vector_type(8))) _Float16 f16x8;
typedef __attribute__((ext_vector_type(4))) float    f32x4;

__device__ __forceinline__ f32x4 mfma16(f16x8 a, f16x8 b, f32x4 c) {
    return __builtin_amdgcn_mfma_f32_16x16x32_f16(a, b, c, 0, 0, 0);
}
__device__ __forceinline__ f16x8 cvt8(const float* p) {
    const float4 a0 = *(const float4*)p;
    const float4 a1 = *(const float4*)(p + 4);
    f16x8 v;
    v[0] = (f16)a0.x; v[1] = (f16)a0.y; v[2] = (f16)a0.z; v[3] = (f16)a0.w;
    v[4] = (f16)a1.x; v[5] = (f16)a1.y; v[6] = (f16)a1.z; v[7] = (f16)a1.w;
    return v;
}

// ---------------------------------------------------------------- utility
__global__ __launch_bounds__(256) void zero_f32(float4* p, long n4) {
    long i = (long)blockIdx.x * blockDim.x + threadIdx.x;
    const long stride = (long)gridDim.x * blockDim.x;
    const float4 z = make_float4(0.f, 0.f, 0.f, 0.f);
    for (; i < n4; i += stride) p[i] = z;
}
__global__ __launch_bounds__(256) void zero_i32(int* p, int n) {
    int i = blockIdx.x * blockDim.x + threadIdx.x;
    if (i < n) p[i] = 0;
}
__global__ __launch_bounds__(256)
void cvt_f16_kernel(const float* __restrict__ x, f16* __restrict__ y, long n8) {
    long i = blockIdx.x * 256 + threadIdx.x;
    const long stride = (long)gridDim.x * 256;
    for (; i < n8; i += stride) *(f16x8*)(y + i * 8) = cvt8(x + i * 8);
}
// pack w[K][HD] f32 -> frags [kt][wv][ht][lane][8] f16 (frag id = kt*8+wv*2+ht)
__global__ __launch_bounds__(256)
void pack_w_kernel(const float* __restrict__ w, f16* __restrict__ wp, int KT) {
    const int idx = blockIdx.x * 256 + threadIdx.x;
    if (idx >= KT * 8 * 64) return;
    const int l  = idx & 63;
    const int fr = idx >> 6;
    const int ht = fr & 1, wv = (fr >> 1) & 3, kt = fr >> 3;
    const int li = l & 15, q = l >> 4;
    const float* p = w + (size_t)(32 * kt + 8 * q) * HD + 32 * wv + 16 * ht + li;
    f16x8 v;
#pragma unroll
    for (int e2 = 0; e2 < 8; ++e2) v[e2] = (f16)p[(size_t)e2 * HD];
    *(f16x8*)(wp + (size_t)idx * 8) = v;
}

// ---------------------------------------------------------------- CSR build
__global__ __launch_bounds__(256)
void hist_kernel(const int* __restrict__ eidx, int* __restrict__ rank,
                 int* __restrict__ cnt, int E) {
    int e = blockIdx.x * 256 + threadIdx.x;
    if (e < E) rank[e] = atomicAdd(&cnt[eidx[E + e]], 1);
}
__global__ __launch_bounds__(1024)
void scan_kernel(const int* __restrict__ cnt, int* __restrict__ rs, int N) {
    __shared__ int wsum[16];
    __shared__ int s_carry;
    const int t = threadIdx.x, lane = t & 63, wid = t >> 6;
    if (t == 0) s_carry = 0;
    __syncthreads();
    for (int base = 0; base < N; base += 1024) {
        const int i = base + t;
        const int v = (i < N) ? cnt[i] : 0;
        int incl = v;
#pragma unroll
        for (int off = 1; off < 64; off <<= 1) {
            int u = __shfl_up(incl, off, 64);
            if (lane >= off) incl += u;
        }
        if (lane == 63) wsum[wid] = incl;
        __syncthreads();
        if (t == 0) {
            int s = 0;
#pragma unroll
            for (int w = 0; w < 16; ++w) { int x = wsum[w]; wsum[w] = s; s += x; }
        }
        __syncthreads();
        const int carry = s_carry;
        if (i < N) rs[i] = carry + wsum[wid] + incl - v;
        __syncthreads();
        if (t == 1023) s_carry = carry + wsum[15] + incl;
        __syncthreads();
    }
    if (threadIdx.x == 0) rs[N] = s_carry;
}
__global__ __launch_bounds__(256)
void pos_kernel(const int* __restrict__ eidx, const int* __restrict__ rs,
                int* __restrict__ pos, int E) {
    int e = blockIdx.x * 256 + threadIdx.x;
    if (e < E) pos[e] = rs[eidx[E + e]] + pos[e];
}

// ---------------------------------------------------------------- edges
// MODE 0: fp32 atomic scatter into agg.  MODE 1: f16 row store at m[pos[e]].
template <int MODE>
__global__ __launch_bounds__(256, 4)
void edge_kernel(const f16*   __restrict__ h16,
                 const int*   __restrict__ eidx,
                 const float* __restrict__ ea,
                 const f16*   __restrict__ w1p,   // packed frags, KT=9
                 const float* __restrict__ b1,
                 const f16*   __restrict__ w2p,   // packed frags, KT=4
                 const float* __restrict__ b2,
                 void*        __restrict__ aggm,  // MODE0: float* ; MODE1: f16*
                 const int*   __restrict__ pos,
                 int E)
{
    __shared__ __align__(16) f16 sA[BME * PAD_E];   // 37888 B; sT aliases
    __shared__ int sIdx[BME];

    const int t  = threadIdx.x;
    const int l  = t & 63;
    const int wv = t >> 6;
    const int li = l & 15;
    const int q  = l >> 4;
    const int ebase = blockIdx.x * BME;

    if (t < BME) {
        const int ec = min(ebase + t, E - 1);
        sIdx[t] = (MODE == 0) ? eidx[E + ec] : pos[ec];
    }

    // ---- stage sA[edge][0..288) = [h16[src] | h16[dst] | cvt(ea)] ----
    {
        const int r  = t >> 2;
        const int q4 = t & 3;
        const int ec = min(ebase + r, E - 1);
        const int src = eidx[ec];
        const int dst = eidx[E + ec];
        const f16* hs = h16 + (size_t)src * HD;
        const f16* hd = h16 + (size_t)dst * HD;
        const float* eap = ea + (size_t)ec * ED;
        f16* row = sA + r * PAD_E;
#pragma unroll
        for (int i = 0; i < 9; ++i) {
            const int c = q4 * 72 + i * 8;
            f16x8 v;
            if (c < 2 * HD) v = *(const f16x8*)((c < HD) ? (hs + c) : (hd + c - HD));
            else            v = cvt8(eap + (c - 2 * HD));
            *(f16x8*)(row + c) = v;
        }
    }
    __syncthreads();

    // ---- GEMM1: out1[hid][edge], K=288, A-frags streamed from w1p ----
    f32x4 acc[2][4];
#pragma unroll
    for (int i = 0; i < 2; ++i)
#pragma unroll
        for (int j = 0; j < 4; ++j) acc[i][j] = (f32x4){0.f, 0.f, 0.f, 0.f};

#pragma unroll 3
    for (int kt = 0; kt < 9; ++kt) {
        const f16x8 a0 = *(const f16x8*)(w1p + ((size_t)(kt * 8 + wv * 2 + 0) * 64 + l) * 8);
        const f16x8 a1 = *(const f16x8*)(w1p + ((size_t)(kt * 8 + wv * 2 + 1) * 64 + l) * 8);
#pragma unroll
        for (int et = 0; et < 4; ++et) {
            const f16x8 b = *(const f16x8*)(sA + (16 * et + li) * PAD_E + 32 * kt + 8 * q);
            acc[0][et] = mfma16(a0, b, acc[0][et]);
            acc[1][et] = mfma16(a1, b, acc[1][et]);
        }
    }
    __syncthreads();   // done reading sA

    // ---- epilogue1: +b1, relu -> f16 sT[edge][hid] (aliases sA) ----
    f16* sT = sA;
#pragma unroll
    for (int ht = 0; ht < 2; ++ht) {
        const int hidb = 32 * wv + 16 * ht + 4 * q;
        const float4 bb = *(const float4*)(b1 + hidb);
#pragma unroll
        for (int et = 0; et < 4; ++et) {
            const f32x4 v = acc[ht][et];
            float x0 = v[0] + bb.x, x1 = v[1] + bb.y,
                  x2 = v[2] + bb.z, x3 = v[3] + bb.w;
            x0 = x0 > 0.f ? x0 : 0.f;  x1 = x1 > 0.f ? x1 : 0.f;
            x2 = x2 > 0.f ? x2 : 0.f;  x3 = x3 > 0.f ? x3 : 0.f;
            f16x4 o; o[0] = (f16)x0; o[1] = (f16)x1; o[2] = (f16)x2; o[3] = (f16)x3;
            *(f16x4*)(sT + (16 * et + li) * PAD_T + hidb) = o;
        }
    }
    __syncthreads();

    // ---- GEMM2: K=128 ----
    f32x4 acc2[2][4];
#pragma unroll
    for (int i = 0; i < 2; ++i)
#pragma unroll
        for (int j = 0; j < 4; ++j) acc2[i][j] = (f32x4){0.f, 0.f, 0.f, 0.f};

#pragma unroll
    for (int kt = 0; kt < 4; ++kt) {
        const f16x8 a0 = *(const f16x8*)(w2p + ((size_t)(kt * 8 + wv * 2 + 0) * 64 + l) * 8);
        const f16x8 a1 = *(const f16x8*)(w2p + ((size_t)(kt * 8 + wv * 2 + 1) * 64 + l) * 8);
#pragma unroll
        for (int et = 0; et < 4; ++et) {
            const f16x8 b = *(const f16x8*)(sT + (16 * et + li) * PAD_T + 32 * kt + 8 * q);
            acc2[0][et] = mfma16(a0, b, acc2[0][et]);
            acc2[1][et] = mfma16(a1, b, acc2[1][et]);
        }
    }

    if (MODE == 0) {
        float* agg = (float*)aggm;
#pragma unroll
        for (int ht = 0; ht < 2; ++ht) {
            const int hidb = 32 * wv + 16 * ht + 4 * q;
            const float4 bb = *(const float4*)(b2 + hidb);
#pragma unroll
            for (int et = 0; et < 4; ++et) {
                const int edge = 16 * et + li;
                if (ebase + edge < E) {
                    float* p = agg + (size_t)sIdx[edge] * HD + hidb;
                    const f32x4 v = acc2[ht][et];
                    atomicAdd(p + 0, v[0] + bb.x);
                    atomicAdd(p + 1, v[1] + bb.y);
                    atomicAdd(p + 2, v[2] + bb.z);
                    atomicAdd(p + 3, v[3] + bb.w);
                }
            }
        }
    } else {
        __syncthreads();   // GEMM2 done reading sT
#pragma unroll
        for (int ht = 0; ht < 2; ++ht) {
            const int hidb = 32 * wv + 16 * ht + 4 * q;
            const float4 bb = *(const float4*)(b2 + hidb);
#pragma unroll
            for (int et = 0; et < 4; ++et) {
                const f32x4 v = acc2[ht][et];
                f16x4 o;
                o[0] = (f16)(v[0] + bb.x); o[1] = (f16)(v[1] + bb.y);
                o[2] = (f16)(v[2] + bb.z); o[3] = (f16)(v[3] + bb.w);
                *(f16x4*)(sT + (16 * et + li) * PAD_T + hidb) = o;
            }
        }
        __syncthreads();
        f16* m = (f16*)aggm;
#pragma unroll
        for (int i = 0; i < 4; ++i) {
            const int idx = t + i * 256;          // 0..1023
            const int row = idx >> 4;             // 0..63
            const int c8  = (idx & 15) * 8;
            if (ebase + row < E) {
                const f16x8 v = *(const f16x8*)(sT + row * PAD_T + c8);
                *(f16x8*)(m + (size_t)sIdx[row] * HD + c8) = v;
            }
        }
    }
}

// ---------------------------------------------------------------- gather
// one wave per node: sum f16 segment rows of m -> dense f16 aggb[n] (OUT of place;
// aggb is fully rewritten every call, incl. zeros for degree-0 nodes)
__global__ __launch_bounds__(256)
void gather_kernel(const f16* __restrict__ m, const int* __restrict__ rs,
                   f16* __restrict__ aggb, int N)
{
    const int n = blockIdx.x * 4 + (threadIdx.x >> 6);
    if (n >= N) return;
    const int lane = threadIdx.x & 63;
    const int s = rs[n], e = rs[n + 1];
    const f16* base = m + (size_t)s * HD + lane * 2;
    const int cnt = e - s;
    float a0 = 0.f, b0 = 0.f, a1 = 0.f, b1 = 0.f;
    int j = 0;
    for (; j + 2 <= cnt; j += 2) {
        const f16x2 u = *(const f16x2*)(base + (size_t)j * HD);
        const f16x2 v = *(const f16x2*)(base + (size_t)(j + 1) * HD);
        a0 += (float)u[0]; b0 += (float)u[1];
        a1 += (float)v[0]; b1 += (float)v[1];
    }
    if (j < cnt) {
        const f16x2 u = *(const f16x2*)(base + (size_t)j * HD);
        a0 += (float)u[0]; b0 += (float)u[1];
    }
    f16x2 r; r[0] = (f16)(a0 + a1); r[1] = (f16)(b0 + b1);
    *(f16x2*)(aggb + (size_t)n * HD + lane * 2) = r;
}

// ---------------------------------------------------------------- nodes
// CSR=1: agg half read from dense f16 aggb.  CSR=0: from dense f32 aggf.
template <int CSR>
__global__ __launch_bounds__(256, 2)
void node_kernel(const f16*   __restrict__ h16,
                 const float* __restrict__ h,      // f32 residual
                 const f16*   __restrict__ aggb,
                 const float* __restrict__ aggf,
                 const f16*   __restrict__ w1p,    // KT=8
                 const float* __restrict__ b1,
                 const f16*   __restrict__ w2p,    // KT=4
                 const float* __restrict__ b2,
                 const float* __restrict__ gamma,
                 const float* __restrict__ beta,
                 float*       __restrict__ out,
                 int N)
{
    __shared__ __align__(16) f16 sA[BMN * PAD_N];  // 67584 B; sX aliases
    __shared__ f16   sT[BMN * PAD_T];
    __shared__ float sMV[2 * BMN];

    const int t  = threadIdx.x;
    const int l  = t & 63;
    const int wv = t >> 6;
    const int li = l & 15;
    const int q  = l >> 4;
    const int nbase = blockIdx.x * BMN;

    // ---- stage sA[node][0..256) = [h16 | agg] : 128 f16 per thread ----
    {
        const int r = t >> 1, half = t & 1;
        const int node = min(nbase + r, N - 1);
        f16* rowp = sA + r * PAD_N + half * HD;
        if (half == 0) {
            const f16* src = h16 + (size_t)node * HD;
#pragma unroll
            for (int i = 0; i < 16; ++i)
                *(f16x8*)(rowp + i * 8) = *(const f16x8*)(src + i * 8);
        } else if (CSR) {
            const f16* src = aggb + (size_t)node * HD;
#pragma unroll
            for (int i = 0; i < 16; ++i)
                *(f16x8*)(rowp + i * 8) = *(const f16x8*)(src + i * 8);
        } else {
            const float* src = aggf + (size_t)node * HD;
#pragma unroll
            for (int i = 0; i < 16; ++i)
                *(f16x8*)(rowp + i * 8) = cvt8(src + i * 8);
        }
    }
    __syncthreads();

    // ---- GEMM1: K=256 ----
    f32x4 acc[2][8];
#pragma unroll
    for (int i = 0; i < 2; ++i)
#pragma unroll
        for (int j = 0; j < 8; ++j) acc[i][j] = (f32x4){0.f, 0.f, 0.f, 0.f};

#pragma unroll 2
    for (int kt = 0; kt < 8; ++kt) {
        const f16x8 a0 = *(const f16x8*)(w1p + ((size_t)(kt * 8 + wv * 2 + 0) * 64 + l) * 8);
        const f16x8 a1 = *(const f16x8*)(w1p + ((size_t)(kt * 8 + wv * 2 + 1) * 64 + l) * 8);
#pragma unroll
        for (int et = 0; et < 8; ++et) {
            const f16x8 b = *(const f16x8*)(sA + (16 * et + li) * PAD_N + 32 * kt + 8 * q);
            acc[0][et] = mfma16(a0, b, acc[0][et]);
            acc[1][et] = mfma16(a1, b, acc[1][et]);
        }
    }
    __syncthreads();

    // ---- epilogue1: +b1, relu -> sT ----
#pragma unroll
    for (int ht = 0; ht < 2; ++ht) {
        const int hidb = 32 * wv + 16 * ht + 4 * q;
        const float4 bb = *(const float4*)(b1 + hidb);
#pragma unroll
        for (int et = 0; et < 8; ++et) {
            const f32x4 v = acc[ht][et];
            float x0 = v[0] + bb.x, x1 = v[1] + bb.y,
                  x2 = v[2] + bb.z, x3 = v[3] + bb.w;
            x0 = x0 > 0.f ? x0 : 0.f;  x1 = x1 > 0.f ? x1 : 0.f;
            x2 = x2 > 0.f ? x2 : 0.f;  x3 = x3 > 0.f ? x3 : 0.f;
            f16x4 o; o[0] = (f16)x0; o[1] = (f16)x1; o[2] = (f16)x2; o[3] = (f16)x3;
            *(f16x4*)(sT + (16 * et + li) * PAD_T + hidb) = o;
        }
    }
    __syncthreads();

    // ---- GEMM2: K=128 ----
    f32x4 acc2[2][8];
#pragma unroll
    for (int i = 0; i < 2; ++i)
#pragma unroll
        for (int j = 0; j < 8; ++j) acc2[i][j] = (f32x4){0.f, 0.f, 0.f, 0.f};

#pragma unroll
    for (int kt = 0; kt < 4; ++kt) {
        const f16x8 a0 = *(const f16x8*)(w2p + ((size_t)(kt * 8 + wv * 2 + 0) * 64 + l) * 8);
        const f16x8 a1 = *(const f16x8*)(w2p + ((size_t)(kt * 8 + wv * 2 + 1) * 64 + l) * 8);
#pragma unroll
        for (int et = 0; et < 8; ++et) {
            const f16x8 b = *(const f16x8*)(sT + (16 * et + li) * PAD_T + 32 * kt + 8 * q);
            acc2[0][et] = mfma16(a0, b, acc2[0][et]);
            acc2[1][et] = mfma16(a1, b, acc2[1][et]);
        }
    }
    __syncthreads();   // sA fully dead; sX may overwrite

    // ---- epilogue2: x = upd + b2 + h -> sX f32 (aliases sA) ----
    float* sX = (float*)sA;            // stride 132 f32
#pragma unroll
    for (int ht = 0; ht < 2; ++ht) {
        const int hidb = 32 * wv + 16 * ht + 4 * q;
        const float4 bb = *(const float4*)(b2 + hidb);
#pragma unroll
        for (int et = 0; et < 8; ++et) {
            const int node = 16 * et + li;
            const int nc   = min(nbase + node, N - 1);
            const float4 hv = *(const float4*)(h + (size_t)nc * HD + hidb);
            const f32x4 v = acc2[ht][et];
            f32x4 x;
            x[0] = v[0] + bb.x + hv.x;
            x[1] = v[1] + bb.y + hv.y;
            x[2] = v[2] + bb.z + hv.z;
            x[3] = v[3] + bb.w + hv.w;
            *(f32x4*)(sX + (size_t)node * 132 + hidb) = x;
        }
    }
    __syncthreads();

    // ---- LayerNorm ----
    {
        const int node  = t >> 1;
        const int half2 = t & 1;
        const float* px = sX + node * 132 + half2 * 64;
        float s = 0.f, sq = 0.f;
#pragma unroll
        for (int i = 0; i < 16; ++i) {
            const float4 v = *(const float4*)(px + i * 4);
            s  += v.x + v.y + v.z + v.w;
            sq += v.x * v.x + v.y * v.y + v.z * v.z + v.w * v.w;
        }
        s  += __shfl_xor(s, 1);
        sq += __shfl_xor(sq, 1);
        if (!half2) {
            const float mean = s * (1.f / HD);
            const float var  = sq * (1.f / HD) - mean * mean;
            sMV[node]       = mean;
            sMV[BMN + node] = rsqrtf(var + 1e-5f);
        }
    }
    __syncthreads();

#pragma unroll
    for (int i = 0; i < 16; ++i) {
        const int idx  = t + i * 256;
        const int node = idx >> 5;
        const int c4   = (idx & 31) * 4;
        if (nbase + node < N) {
            const float4 xv = *(const float4*)(sX + node * 132 + c4);
            const float4 g4 = *(const float4*)(gamma + c4);
            const float4 b4 = *(const float4*)(beta + c4);
            const float mean = sMV[node];
            const float rstd = sMV[BMN + node];
            float4 o;
            o.x = (xv.x - mean) * rstd * g4.x + b4.x;
            o.y = (xv.y - mean) * rstd * g4.y + b4.y;
            o.z = (xv.z - mean) * rstd * g4.z + b4.z;
            o.w = (xv.w - mean) * rstd * g4.w + b4.w;
            *(float4*)(out + (size_t)(nbase + node) * HD + c4) = o;
        }
    }
}

// ---------------------------------------------------------------- launch
extern "C" void kernel_launch(void* const* d_in, const int* in_sizes, int n_in,
                              void* d_out, int out_size, void* d_ws, size_t ws_size,
                              hipStream_t stream)
{
    const float* h     = (const float*)d_in[0];
    const int*   eidx  = (const int*)  d_in[1];
    const float* ea    = (const float*)d_in[2];
    const float* ew1   = (const float*)d_in[3];
    const float* eb1   = (const float*)d_in[4];
    const float* ew2   = (const float*)d_in[5];
    const float* eb2   = (const float*)d_in[6];
    const float* nw1   = (const float*)d_in[7];
    const float* nb1   = (const float*)d_in[8];
    const float* nw2   = (const float*)d_in[9];
    const float* nb2   = (const float*)d_in[10];
    const float* gamma = (const float*)d_in[11];
    const float* beta  = (const float*)d_in[12];
    float* out = (float*)d_out;

    const int N = in_sizes[0] / HD;
    const int E = in_sizes[1] / 2;

    size_t off = 0;
    auto alloc = [&](size_t bytes) {
        size_t o = off; off += (bytes + 255) & ~(size_t)255; return o;
    };
    const size_t o_m    = alloc((size_t)E * HD * sizeof(f16));
    const size_t o_agb  = alloc((size_t)N * HD * sizeof(f16));
    const size_t o_h16  = alloc((size_t)N * HD * sizeof(f16));
    const size_t o_pos  = alloc((size_t)E * sizeof(int));
    const size_t o_rs   = alloc((size_t)(N + 1) * sizeof(int));
    const size_t o_cnt  = alloc((size_t)N * sizeof(int));
    const size_t o_w1p  = alloc((size_t)9 * 8 * 64 * 8 * sizeof(f16));
    const size_t o_w2p  = alloc((size_t)4 * 8 * 64 * 8 * sizeof(f16));
    const size_t o_n1p  = alloc((size_t)8 * 8 * 64 * 8 * sizeof(f16));
    const size_t o_n2p  = alloc((size_t)4 * 8 * 64 * 8 * sizeof(f16));
    const bool csr = (off <= ws_size);
    char* ws = (char*)d_ws;

    if (csr) {
        f16* mb   = (f16*)(ws + o_m);
        f16* aggb = (f16*)(ws + o_agb);
        f16* h16  = (f16*)(ws + o_h16);
        int* pos  = (int*)(ws + o_pos);
        int* rs   = (int*)(ws + o_rs);
        int* cnt  = (int*)(ws + o_cnt);
        f16* w1p  = (f16*)(ws + o_w1p);
        f16* w2p  = (f16*)(ws + o_w2p);
        f16* n1p  = (f16*)(ws + o_n1p);
        f16* n2p  = (f16*)(ws + o_n2p);

        zero_i32<<<(N + 255) / 256, 256, 0, stream>>>(cnt, N);
        hist_kernel<<<(E + 255) / 256, 256, 0, stream>>>(eidx, pos, cnt, E);
        scan_kernel<<<1, 1024, 0, stream>>>(cnt, rs, N);
        pos_kernel<<<(E + 255) / 256, 256, 0, stream>>>(eidx, rs, pos, E);
        cvt_f16_kernel<<<2048, 256, 0, stream>>>(h, h16, (long)N * HD / 8);
        pack_w_kernel<<<18, 256, 0, stream>>>(ew1, w1p, 9);
        pack_w_kernel<<<8,  256, 0, stream>>>(ew2, w2p, 4);
        pack_w_kernel<<<16, 256, 0, stream>>>(nw1, n1p, 8);
        pack_w_kernel<<<8,  256, 0, stream>>>(nw2, n2p, 4);
        edge_kernel<1><<<(E + BME - 1) / BME, 256, 0, stream>>>(
            h16, eidx, ea, w1p, eb1, w2p, eb2, (void*)mb, pos, E);
        gather_kernel<<<(N + 3) / 4, 256, 0, stream>>>(mb, rs, aggb, N);
        node_kernel<1><<<(N + BMN - 1) / BMN, 256, 0, stream>>>(
            h16, h, aggb, nullptr, n1p, nb1, n2p, nb2, gamma, beta, out, N);
    } else {
        // fallback: dense f32 atomic aggregation
        size_t foff = 0;
        auto falloc = [&](size_t bytes) {
            size_t o = foff; foff += (bytes + 255) & ~(size_t)255; return o;
        };
        float* agg = (float*)(ws + falloc((size_t)N * HD * sizeof(float)));
        f16*   h16 = (f16*)  (ws + falloc((size_t)N * HD * sizeof(f16)));
        f16*   w1p = (f16*)  (ws + falloc((size_t)9 * 8 * 64 * 8 * sizeof(f16)));
        f16*   w2p = (f16*)  (ws + falloc((size_t)4 * 8 * 64 * 8 * sizeof(f16)));
        f16*   n1p = (f16*)  (ws + falloc((size_t)8 * 8 * 64 * 8 * sizeof(f16)));
        f16*   n2p = (f16*)  (ws + falloc((size_t)4 * 8 * 64 * 8 * sizeof(f16)));

        zero_f32<<<1024, 256, 0, stream>>>((float4*)agg, (long)N * HD / 4);
        cvt_f16_kernel<<<2048, 256, 0, stream>>>(h, h16, (long)N * HD / 8);
        pack_w_kernel<<<18, 256, 0, stream>>>(ew1, w1p, 9);
        pack_w_kernel<<<8,  256, 0, stream>>>(ew2, w2p, 4);
        pack_w_kernel<<<16, 256, 0, stream>>>(nw1, n1p, 8);
        pack_w_kernel<<<8,  256, 0, stream>>>(nw2, n2p, 4);
        edge_kernel<0><<<(E + BME - 1) / BME, 256, 0, stream>>>(
            h16, eidx, ea, w1p, eb1, w2p, eb2, (void*)agg, nullptr, E);
        node_kernel<0><<<(N + BMN - 1) / BMN, 256, 0, stream>>>(
            h16, h, nullptr, agg, n1p, nb1, n2p, nb2, gamma, beta, out, N);
    }
}

// Round 7
// 297.972 us; speedup vs baseline: 4.6021x; 1.0974x over previous
//
#include <hip/hip_runtime.h>
#include <cstdint>

#define HD 128
#define ED 32
#define BME 64            // edges per tile (edge kernel)
#define BMN 128           // nodes per block (node kernel)
#define PAD_E 296         // sA row stride f16, edge: 288+8
#define PAD_N 264         // sA row stride f16, node: 256+8
#define PAD_T 136         // sT row stride f16: 128+8
#define EGRID 512         // persistent edge blocks (2 per CU)

typedef _Float16 f16;
typedef __attribute__((ext_vector_type(2))) _Float16 f16x2;
typedef __attribute__((ext_vector_type(4))) _Float16 f16x4;
typedef __attribute__((ext_vector_type(8))) _Float16 f16x8;
typedef __attribute__((ext_vector_type(4))) float    f32x4;

__device__ __forceinline__ f32x4 mfma16(f16x8 a, f16x8 b, f32x4 c) {
    return __builtin_amdgcn_mfma_f32_16x16x32_f16(a, b, c, 0, 0, 0);
}
__device__ __forceinline__ f16x8 cvt8(const float* p) {
    const float4 a0 = *(const float4*)p;
    const float4 a1 = *(const float4*)(p + 4);
    f16x8 v;
    v[0] = (f16)a0.x; v[1] = (f16)a0.y; v[2] = (f16)a0.z; v[3] = (f16)a0.w;
    v[4] = (f16)a1.x; v[5] = (f16)a1.y; v[6] = (f16)a1.z; v[7] = (f16)a1.w;
    return v;
}

// ---------------------------------------------------------------- utility
__global__ __launch_bounds__(256) void zero_f32(float4* p, long n4) {
    long i = (long)blockIdx.x * blockDim.x + threadIdx.x;
    const long stride = (long)gridDim.x * blockDim.x;
    const float4 z = make_float4(0.f, 0.f, 0.f, 0.f);
    for (; i < n4; i += stride) p[i] = z;
}
__global__ __launch_bounds__(256) void zero_i32(int* p, int n) {
    int i = blockIdx.x * blockDim.x + threadIdx.x;
    if (i < n) p[i] = 0;
}
__global__ __launch_bounds__(256)
void cvt_f16_kernel(const float* __restrict__ x, f16* __restrict__ y, long n8) {
    long i = blockIdx.x * 256 + threadIdx.x;
    const long stride = (long)gridDim.x * 256;
    for (; i < n8; i += stride) *(f16x8*)(y + i * 8) = cvt8(x + i * 8);
}
// pack all 4 weight mats -> frag order [kt][wv][ht][lane][8] f16
// blocks: 0..17 ew1(KT9), 18..25 ew2(KT4), 26..41 nw1(KT8), 42..49 nw2(KT4)
__global__ __launch_bounds__(256)
void pack_all_kernel(const float* __restrict__ ew1, const float* __restrict__ ew2,
                     const float* __restrict__ nw1, const float* __restrict__ nw2,
                     f16* __restrict__ w1p, f16* __restrict__ w2p,
                     f16* __restrict__ n1p, f16* __restrict__ n2p)
{
    const int b = blockIdx.x;
    const float* w; f16* wp; int base;
    if (b < 18)      { w = ew1; wp = w1p; base = b; }
    else if (b < 26) { w = ew2; wp = w2p; base = b - 18; }
    else if (b < 42) { w = nw1; wp = n1p; base = b - 26; }
    else             { w = nw2; wp = n2p; base = b - 42; }
    const int idx = base * 256 + threadIdx.x;
    const int l  = idx & 63;
    const int fr = idx >> 6;
    const int ht = fr & 1, wvv = (fr >> 1) & 3, kt = fr >> 3;
    const int lii = l & 15, qq = l >> 4;
    const float* p = w + (size_t)(32 * kt + 8 * qq) * HD + 32 * wvv + 16 * ht + lii;
    f16x8 v;
#pragma unroll
    for (int e2 = 0; e2 < 8; ++e2) v[e2] = (f16)p[(size_t)e2 * HD];
    *(f16x8*)(wp + (size_t)idx * 8) = v;
}

// ---------------------------------------------------------------- CSR build
__global__ __launch_bounds__(256)
void hist_kernel(const int* __restrict__ eidx, int* __restrict__ rank,
                 int* __restrict__ cnt, int E) {
    int e = blockIdx.x * 256 + threadIdx.x;
    if (e < E) rank[e] = atomicAdd(&cnt[eidx[E + e]], 1);
}
__global__ __launch_bounds__(1024)
void scan_kernel(const int* __restrict__ cnt, int* __restrict__ rs, int N) {
    __shared__ int wsum[16];
    __shared__ int s_carry;
    const int t = threadIdx.x, lane = t & 63, wid = t >> 6;
    if (t == 0) s_carry = 0;
    __syncthreads();
    for (int base = 0; base < N; base += 1024) {
        const int i = base + t;
        const int v = (i < N) ? cnt[i] : 0;
        int incl = v;
#pragma unroll
        for (int off = 1; off < 64; off <<= 1) {
            int u = __shfl_up(incl, off, 64);
            if (lane >= off) incl += u;
        }
        if (lane == 63) wsum[wid] = incl;
        __syncthreads();
        if (t == 0) {
            int s = 0;
#pragma unroll
            for (int w = 0; w < 16; ++w) { int x = wsum[w]; wsum[w] = s; s += x; }
        }
        __syncthreads();
        const int carry = s_carry;
        if (i < N) rs[i] = carry + wsum[wid] + incl - v;
        __syncthreads();
        if (t == 1023) s_carry = carry + wsum[15] + incl;
        __syncthreads();
    }
    if (threadIdx.x == 0) rs[N] = s_carry;
}
__global__ __launch_bounds__(256)
void pos_kernel(const int* __restrict__ eidx, const int* __restrict__ rs,
                int* __restrict__ pos, int E) {
    int e = blockIdx.x * 256 + threadIdx.x;
    if (e < E) pos[e] = rs[eidx[E + e]] + pos[e];
}

// ---------------------------------------------------------------- edges
// Persistent: weights in registers, grid-stride over tiles, stage-ahead-by-1.
// MODE 0: fp32 atomic scatter into agg.  MODE 1: f16 row store at m[pos[e]].
template <int MODE>
__global__ __launch_bounds__(256, 2)
void edge_kernel(const f16*   __restrict__ h16,
                 const int*   __restrict__ eidx,
                 const float* __restrict__ ea,
                 const f16*   __restrict__ w1p,   // packed frags, KT=9
                 const float* __restrict__ b1,
                 const f16*   __restrict__ w2p,   // packed frags, KT=4
                 const float* __restrict__ b2,
                 void*        __restrict__ aggm,  // MODE0: float* ; MODE1: f16*
                 const int*   __restrict__ pos,
                 int E, int ntiles)
{
    __shared__ __align__(16) f16 sA[BME * PAD_E];   // 37888 B
    __shared__ __align__(16) f16 sT[BME * PAD_T];   // 17408 B
    __shared__ int sIdx[2][BME];

    const int t  = threadIdx.x;
    const int l  = t & 63;
    const int wv = t >> 6;
    const int li = l & 15;
    const int q  = l >> 4;
    const int r  = t >> 2;            // staging row (0..63)
    const int q4 = t & 3;             // staging quarter

    // ---- weights -> registers, once per block ----
    f16x8 A1[2][9], A2[2][4];
#pragma unroll
    for (int ht = 0; ht < 2; ++ht) {
#pragma unroll
        for (int kt = 0; kt < 9; ++kt)
            A1[ht][kt] = *(const f16x8*)(w1p + ((size_t)(kt * 8 + wv * 2 + ht) * 64 + l) * 8);
#pragma unroll
        for (int kt = 0; kt < 4; ++kt)
            A2[ht][kt] = *(const f16x8*)(w2p + ((size_t)(kt * 8 + wv * 2 + ht) * 64 + l) * 8);
    }

    // ---- prefetch lambda: tile data -> registers ----
    f16x8 d[9];
    int   psr = 0;
    auto prefetch = [&](int tile) {
        const int ec  = min(tile * BME + r, E - 1);
        const int src = eidx[ec];
        const int dst = eidx[E + ec];
        psr = (MODE == 0) ? dst : pos[ec];
        const f16* hs = h16 + (size_t)src * HD;
        const f16* hd = h16 + (size_t)dst * HD;
        const float* eap = ea + (size_t)ec * ED;
#pragma unroll
        for (int i = 0; i < 9; ++i) {
            const int c = q4 * 72 + i * 8;
            d[i] = (c < HD)     ? *(const f16x8*)(hs + c)
                 : (c < 2 * HD) ? *(const f16x8*)(hd + c - HD)
                                : cvt8(eap + (c - 2 * HD));
        }
    };

    int tb = blockIdx.x;
    if (tb < ntiles) prefetch(tb);
    int par = 0;

    for (; tb < ntiles; tb += gridDim.x, par ^= 1) {
        // ---- stage regs -> sA (safe: last sA read was GEMM1, 3 barriers ago) ----
#pragma unroll
        for (int i = 0; i < 9; ++i)
            *(f16x8*)(sA + r * PAD_E + q4 * 72 + i * 8) = d[i];
        if (q4 == 0) sIdx[par][r] = psr;
        __syncthreads();                              // S1: sA ready

        const int nt = tb + gridDim.x;
        if (nt < ntiles) prefetch(nt);                // hide under GEMMs

        // ---- GEMM1: K=288 ----
        f32x4 acc[2][4];
#pragma unroll
        for (int i = 0; i < 2; ++i)
#pragma unroll
            for (int j = 0; j < 4; ++j) acc[i][j] = (f32x4){0.f, 0.f, 0.f, 0.f};
#pragma unroll
        for (int kt = 0; kt < 9; ++kt) {
#pragma unroll
            for (int et = 0; et < 4; ++et) {
                const f16x8 b = *(const f16x8*)(sA + (16 * et + li) * PAD_E + 32 * kt + 8 * q);
                acc[0][et] = mfma16(A1[0][kt], b, acc[0][et]);
                acc[1][et] = mfma16(A1[1][kt], b, acc[1][et]);
            }
        }

        // ---- epilogue1: +b1, relu -> sT ----
#pragma unroll
        for (int ht = 0; ht < 2; ++ht) {
            const int hidb = 32 * wv + 16 * ht + 4 * q;
            const float4 bb = *(const float4*)(b1 + hidb);
#pragma unroll
            for (int et = 0; et < 4; ++et) {
                const f32x4 v = acc[ht][et];
                float x0 = v[0] + bb.x, x1 = v[1] + bb.y,
                      x2 = v[2] + bb.z, x3 = v[3] + bb.w;
                x0 = x0 > 0.f ? x0 : 0.f;  x1 = x1 > 0.f ? x1 : 0.f;
                x2 = x2 > 0.f ? x2 : 0.f;  x3 = x3 > 0.f ? x3 : 0.f;
                f16x4 o; o[0] = (f16)x0; o[1] = (f16)x1; o[2] = (f16)x2; o[3] = (f16)x3;
                *(f16x4*)(sT + (16 * et + li) * PAD_T + hidb) = o;
            }
        }
        __syncthreads();                              // S2: sT ready

        // ---- GEMM2: K=128 ----
        f32x4 acc2[2][4];
#pragma unroll
        for (int i = 0; i < 2; ++i)
#pragma unroll
            for (int j = 0; j < 4; ++j) acc2[i][j] = (f32x4){0.f, 0.f, 0.f, 0.f};
#pragma unroll
        for (int kt = 0; kt < 4; ++kt) {
#pragma unroll
            for (int et = 0; et < 4; ++et) {
                const f16x8 b = *(const f16x8*)(sT + (16 * et + li) * PAD_T + 32 * kt + 8 * q);
                acc2[0][et] = mfma16(A2[0][kt], b, acc2[0][et]);
                acc2[1][et] = mfma16(A2[1][kt], b, acc2[1][et]);
            }
        }

        if (MODE == 0) {
            float* agg = (float*)aggm;
#pragma unroll
            for (int ht = 0; ht < 2; ++ht) {
                const int hidb = 32 * wv + 16 * ht + 4 * q;
                const float4 bb = *(const float4*)(b2 + hidb);
#pragma unroll
                for (int et = 0; et < 4; ++et) {
                    const int edge = 16 * et + li;
                    if (tb * BME + edge < E) {
                        float* p = agg + (size_t)sIdx[par][edge] * HD + hidb;
                        const f32x4 v = acc2[ht][et];
                        atomicAdd(p + 0, v[0] + bb.x);
                        atomicAdd(p + 1, v[1] + bb.y);
                        atomicAdd(p + 2, v[2] + bb.z);
                        atomicAdd(p + 3, v[3] + bb.w);
                    }
                }
            }
            __syncthreads();     // keep sT/sA lifetimes tile-local
        } else {
            __syncthreads();                          // S3: GEMM2 done reading sT
#pragma unroll
            for (int ht = 0; ht < 2; ++ht) {
                const int hidb = 32 * wv + 16 * ht + 4 * q;
                const float4 bb = *(const float4*)(b2 + hidb);
#pragma unroll
                for (int et = 0; et < 4; ++et) {
                    const f32x4 v = acc2[ht][et];
                    f16x4 o;
                    o[0] = (f16)(v[0] + bb.x); o[1] = (f16)(v[1] + bb.y);
                    o[2] = (f16)(v[2] + bb.z); o[3] = (f16)(v[3] + bb.w);
                    *(f16x4*)(sT + (16 * et + li) * PAD_T + hidb) = o;
                }
            }
            __syncthreads();                          // S4: result tile ready
            f16* m = (f16*)aggm;
#pragma unroll
            for (int i = 0; i < 4; ++i) {
                const int idx = t + i * 256;          // 0..1023
                const int row = idx >> 4;             // 0..63
                const int c8  = (idx & 15) * 8;
                if (tb * BME + row < E) {
                    const f16x8 v = *(const f16x8*)(sT + row * PAD_T + c8);
                    *(f16x8*)(m + (size_t)sIdx[par][row] * HD + c8) = v;
                }
            }
        }
    }
}

// ---------------------------------------------------------------- gather
__global__ __launch_bounds__(256)
void gather_kernel(const f16* __restrict__ m, const int* __restrict__ rs,
                   f16* __restrict__ aggb, int N)
{
    const int n = blockIdx.x * 4 + (threadIdx.x >> 6);
    if (n >= N) return;
    const int lane = threadIdx.x & 63;
    const int s = rs[n], e = rs[n + 1];
    const f16* base = m + (size_t)s * HD + lane * 2;
    const int cnt = e - s;
    float a0 = 0.f, b0 = 0.f, a1 = 0.f, b1 = 0.f;
    int j = 0;
    for (; j + 2 <= cnt; j += 2) {
        const f16x2 u = *(const f16x2*)(base + (size_t)j * HD);
        const f16x2 v = *(const f16x2*)(base + (size_t)(j + 1) * HD);
        a0 += (float)u[0]; b0 += (float)u[1];
        a1 += (float)v[0]; b1 += (float)v[1];
    }
    if (j < cnt) {
        const f16x2 u = *(const f16x2*)(base + (size_t)j * HD);
        a0 += (float)u[0]; b0 += (float)u[1];
    }
    f16x2 rr; rr[0] = (f16)(a0 + a1); rr[1] = (f16)(b0 + b1);
    *(f16x2*)(aggb + (size_t)n * HD + lane * 2) = rr;
}

// ---------------------------------------------------------------- nodes
// Weights in registers; sT aliases sA (saves 34.8 KB -> 2 blocks/CU).
// CSR=1: agg half from dense f16 aggb.  CSR=0: from dense f32 aggf.
template <int CSR>
__global__ __launch_bounds__(256, 2)
void node_kernel(const f16*   __restrict__ h16,
                 const float* __restrict__ h,      // f32 residual
                 const f16*   __restrict__ aggb,
                 const float* __restrict__ aggf,
                 const f16*   __restrict__ w1p,    // KT=8
                 const float* __restrict__ b1,
                 const f16*   __restrict__ w2p,    // KT=4
                 const float* __restrict__ b2,
                 const float* __restrict__ gamma,
                 const float* __restrict__ beta,
                 float*       __restrict__ out,
                 int N)
{
    __shared__ __align__(16) f16 sA[BMN * PAD_N];  // 67584 B; sT & sX alias
    __shared__ float sMV[2 * BMN];

    const int t  = threadIdx.x;
    const int l  = t & 63;
    const int wv = t >> 6;
    const int li = l & 15;
    const int q  = l >> 4;
    const int nbase = blockIdx.x * BMN;

    // ---- stage sA[node][0..256) = [h16 | agg] : 128 f16 per thread ----
    {
        const int r = t >> 1, half = t & 1;
        const int node = min(nbase + r, N - 1);
        f16* rowp = sA + r * PAD_N + half * HD;
        if (half == 0) {
            const f16* src = h16 + (size_t)node * HD;
#pragma unroll
            for (int i = 0; i < 16; ++i)
                *(f16x8*)(rowp + i * 8) = *(const f16x8*)(src + i * 8);
        } else if (CSR) {
            const f16* src = aggb + (size_t)node * HD;
#pragma unroll
            for (int i = 0; i < 16; ++i)
                *(f16x8*)(rowp + i * 8) = *(const f16x8*)(src + i * 8);
        } else {
            const float* src = aggf + (size_t)node * HD;
#pragma unroll
            for (int i = 0; i < 16; ++i)
                *(f16x8*)(rowp + i * 8) = cvt8(src + i * 8);
        }
    }

    // ---- A1 -> registers (overlaps staging) ----
    f16x8 A1[2][8];
#pragma unroll
    for (int ht = 0; ht < 2; ++ht)
#pragma unroll
        for (int kt = 0; kt < 8; ++kt)
            A1[ht][kt] = *(const f16x8*)(w1p + ((size_t)(kt * 8 + wv * 2 + ht) * 64 + l) * 8);
    __syncthreads();                                  // S1

    // ---- GEMM1: K=256 ----
    f32x4 acc[2][8];
#pragma unroll
    for (int i = 0; i < 2; ++i)
#pragma unroll
        for (int j = 0; j < 8; ++j) acc[i][j] = (f32x4){0.f, 0.f, 0.f, 0.f};
#pragma unroll
    for (int kt = 0; kt < 8; ++kt) {
#pragma unroll
        for (int et = 0; et < 8; ++et) {
            const f16x8 b = *(const f16x8*)(sA + (16 * et + li) * PAD_N + 32 * kt + 8 * q);
            acc[0][et] = mfma16(A1[0][kt], b, acc[0][et]);
            acc[1][et] = mfma16(A1[1][kt], b, acc[1][et]);
        }
    }
    __syncthreads();                                  // S2: sA reads done (alias!)

    // ---- A2 -> registers (A1 dead, regs reused) ----
    f16x8 A2[2][4];
#pragma unroll
    for (int ht = 0; ht < 2; ++ht)
#pragma unroll
        for (int kt = 0; kt < 4; ++kt)
            A2[ht][kt] = *(const f16x8*)(w2p + ((size_t)(kt * 8 + wv * 2 + ht) * 64 + l) * 8);

    // ---- epilogue1: +b1, relu -> sT (aliases sA) ----
    f16* sT = sA;
#pragma unroll
    for (int ht = 0; ht < 2; ++ht) {
        const int hidb = 32 * wv + 16 * ht + 4 * q;
        const float4 bb = *(const float4*)(b1 + hidb);
#pragma unroll
        for (int et = 0; et < 8; ++et) {
            const f32x4 v = acc[ht][et];
            float x0 = v[0] + bb.x, x1 = v[1] + bb.y,
                  x2 = v[2] + bb.z, x3 = v[3] + bb.w;
            x0 = x0 > 0.f ? x0 : 0.f;  x1 = x1 > 0.f ? x1 : 0.f;
            x2 = x2 > 0.f ? x2 : 0.f;  x3 = x3 > 0.f ? x3 : 0.f;
            f16x4 o; o[0] = (f16)x0; o[1] = (f16)x1; o[2] = (f16)x2; o[3] = (f16)x3;
            *(f16x4*)(sT + (16 * et + li) * PAD_T + hidb) = o;
        }
    }
    __syncthreads();                                  // S3: sT ready

    // ---- GEMM2: K=128 ----
    f32x4 acc2[2][8];
#pragma unroll
    for (int i = 0; i < 2; ++i)
#pragma unroll
        for (int j = 0; j < 8; ++j) acc2[i][j] = (f32x4){0.f, 0.f, 0.f, 0.f};
#pragma unroll
    for (int kt = 0; kt < 4; ++kt) {
#pragma unroll
        for (int et = 0; et < 8; ++et) {
            const f16x8 b = *(const f16x8*)(sT + (16 * et + li) * PAD_T + 32 * kt + 8 * q);
            acc2[0][et] = mfma16(A2[0][kt], b, acc2[0][et]);
            acc2[1][et] = mfma16(A2[1][kt], b, acc2[1][et]);
        }
    }
    __syncthreads();                                  // S4: sT reads done

    // ---- epilogue2: x = upd + b2 + h -> sX f32 (aliases sA) ----
    float* sX = (float*)sA;            // stride 132 f32
#pragma unroll
    for (int ht = 0; ht < 2; ++ht) {
        const int hidb = 32 * wv + 16 * ht + 4 * q;
        const float4 bb = *(const float4*)(b2 + hidb);
#pragma unroll
        for (int et = 0; et < 8; ++et) {
            const int node = 16 * et + li;
            const int nc   = min(nbase + node, N - 1);
            const float4 hv = *(const float4*)(h + (size_t)nc * HD + hidb);
            const f32x4 v = acc2[ht][et];
            f32x4 x;
            x[0] = v[0] + bb.x + hv.x;
            x[1] = v[1] + bb.y + hv.y;
            x[2] = v[2] + bb.z + hv.z;
            x[3] = v[3] + bb.w + hv.w;
            *(f32x4*)(sX + (size_t)node * 132 + hidb) = x;
        }
    }
    __syncthreads();                                  // S5

    // ---- LayerNorm ----
    {
        const int node  = t >> 1;
        const int half2 = t & 1;
        const float* px = sX + node * 132 + half2 * 64;
        float s = 0.f, sq = 0.f;
#pragma unroll
        for (int i = 0; i < 16; ++i) {
            const float4 v = *(const float4*)(px + i * 4);
            s  += v.x + v.y + v.z + v.w;
            sq += v.x * v.x + v.y * v.y + v.z * v.z + v.w * v.w;
        }
        s  += __shfl_xor(s, 1);
        sq += __shfl_xor(sq, 1);
        if (!half2) {
            const float mean = s * (1.f / HD);
            const float var  = sq * (1.f / HD) - mean * mean;
            sMV[node]       = mean;
            sMV[BMN + node] = rsqrtf(var + 1e-5f);
        }
    }
    __syncthreads();                                  // S6

#pragma unroll
    for (int i = 0; i < 16; ++i) {
        const int idx  = t + i * 256;
        const int node = idx >> 5;
        const int c4   = (idx & 31) * 4;
        if (nbase + node < N) {
            const float4 xv = *(const float4*)(sX + node * 132 + c4);
            const float4 g4 = *(const float4*)(gamma + c4);
            const float4 b4 = *(const float4*)(beta + c4);
            const float mean = sMV[node];
            const float rstd = sMV[BMN + node];
            float4 o;
            o.x = (xv.x - mean) * rstd * g4.x + b4.x;
            o.y = (xv.y - mean) * rstd * g4.y + b4.y;
            o.z = (xv.z - mean) * rstd * g4.z + b4.z;
            o.w = (xv.w - mean) * rstd * g4.w + b4.w;
            *(float4*)(out + (size_t)(nbase + node) * HD + c4) = o;
        }
    }
}

// ---------------------------------------------------------------- launch
extern "C" void kernel_launch(void* const* d_in, const int* in_sizes, int n_in,
                              void* d_out, int out_size, void* d_ws, size_t ws_size,
                              hipStream_t stream)
{
    const float* h     = (const float*)d_in[0];
    const int*   eidx  = (const int*)  d_in[1];
    const float* ea    = (const float*)d_in[2];
    const float* ew1   = (const float*)d_in[3];
    const float* eb1   = (const float*)d_in[4];
    const float* ew2   = (const float*)d_in[5];
    const float* eb2   = (const float*)d_in[6];
    const float* nw1   = (const float*)d_in[7];
    const float* nb1   = (const float*)d_in[8];
    const float* nw2   = (const float*)d_in[9];
    const float* nb2   = (const float*)d_in[10];
    const float* gamma = (const float*)d_in[11];
    const float* beta  = (const float*)d_in[12];
    float* out = (float*)d_out;

    const int N = in_sizes[0] / HD;
    const int E = in_sizes[1] / 2;
    const int ntiles = (E + BME - 1) / BME;

    size_t off = 0;
    auto alloc = [&](size_t bytes) {
        size_t o = off; off += (bytes + 255) & ~(size_t)255; return o;
    };
    const size_t o_m    = alloc((size_t)E * HD * sizeof(f16));
    const size_t o_agb  = alloc((size_t)N * HD * sizeof(f16));
    const size_t o_h16  = alloc((size_t)N * HD * sizeof(f16));
    const size_t o_pos  = alloc((size_t)E * sizeof(int));
    const size_t o_rs   = alloc((size_t)(N + 1) * sizeof(int));
    const size_t o_cnt  = alloc((size_t)N * sizeof(int));
    const size_t o_w1p  = alloc((size_t)9 * 8 * 64 * 8 * sizeof(f16));
    const size_t o_w2p  = alloc((size_t)4 * 8 * 64 * 8 * sizeof(f16));
    const size_t o_n1p  = alloc((size_t)8 * 8 * 64 * 8 * sizeof(f16));
    const size_t o_n2p  = alloc((size_t)4 * 8 * 64 * 8 * sizeof(f16));
    const bool csr = (off <= ws_size);
    char* ws = (char*)d_ws;

    if (csr) {
        f16* mb   = (f16*)(ws + o_m);
        f16* aggb = (f16*)(ws + o_agb);
        f16* h16  = (f16*)(ws + o_h16);
        int* pos  = (int*)(ws + o_pos);
        int* rs   = (int*)(ws + o_rs);
        int* cnt  = (int*)(ws + o_cnt);
        f16* w1p  = (f16*)(ws + o_w1p);
        f16* w2p  = (f16*)(ws + o_w2p);
        f16* n1p  = (f16*)(ws + o_n1p);
        f16* n2p  = (f16*)(ws + o_n2p);

        zero_i32<<<(N + 255) / 256, 256, 0, stream>>>(cnt, N);
        hist_kernel<<<(E + 255) / 256, 256, 0, stream>>>(eidx, pos, cnt, E);
        scan_kernel<<<1, 1024, 0, stream>>>(cnt, rs, N);
        pos_kernel<<<(E + 255) / 256, 256, 0, stream>>>(eidx, rs, pos, E);
        cvt_f16_kernel<<<2048, 256, 0, stream>>>(h, h16, (long)N * HD / 8);
        pack_all_kernel<<<50, 256, 0, stream>>>(ew1, ew2, nw1, nw2, w1p, w2p, n1p, n2p);
        edge_kernel<1><<<EGRID, 256, 0, stream>>>(
            h16, eidx, ea, w1p, eb1, w2p, eb2, (void*)mb, pos, E, ntiles);
        gather_kernel<<<(N + 3) / 4, 256, 0, stream>>>(mb, rs, aggb, N);
        node_kernel<1><<<(N + BMN - 1) / BMN, 256, 0, stream>>>(
            h16, h, aggb, nullptr, n1p, nb1, n2p, nb2, gamma, beta, out, N);
    } else {
        // fallback: dense f32 atomic aggregation
        size_t foff = 0;
        auto falloc = [&](size_t bytes) {
            size_t o = foff; foff += (bytes + 255) & ~(size_t)255; return o;
        };
        float* agg = (float*)(ws + falloc((size_t)N * HD * sizeof(float)));
        f16*   h16 = (f16*)  (ws + falloc((size_t)N * HD * sizeof(f16)));
        f16*   w1p = (f16*)  (ws + falloc((size_t)9 * 8 * 64 * 8 * sizeof(f16)));
        f16*   w2p = (f16*)  (ws + falloc((size_t)4 * 8 * 64 * 8 * sizeof(f16)));
        f16*   n1p = (f16*)  (ws + falloc((size_t)8 * 8 * 64 * 8 * sizeof(f16)));
        f16*   n2p = (f16*)  (ws + falloc((size_t)4 * 8 * 64 * 8 * sizeof(f16)));

        zero_f32<<<1024, 256, 0, stream>>>((float4*)agg, (long)N * HD / 4);
        cvt_f16_kernel<<<2048, 256, 0, stream>>>(h, h16, (long)N * HD / 8);
        pack_all_kernel<<<50, 256, 0, stream>>>(ew1, ew2, nw1, nw2, w1p, w2p, n1p, n2p);
        edge_kernel<0><<<EGRID, 256, 0, stream>>>(
            h16, eidx, ea, w1p, eb1, w2p, eb2, (void*)agg, nullptr, E, ntiles);
        node_kernel<0><<<(N + BMN - 1) / BMN, 256, 0, stream>>>(
            h16, h, nullptr, agg, n1p, nb1, n2p, nb2, gamma, beta, out, N);
    }
}

// Round 9
// 281.686 us; speedup vs baseline: 4.8682x; 1.0578x over previous
//
#include <hip/hip_runtime.h>
#include <cstdint>

#define HD 128
#define ED 32
#define BME 64            // edges per tile (edge kernel)
#define BMN 128           // nodes per block (node kernel)
#define PAD_N 264         // node sA row stride f16: 256+8
#define PAD_T 136         // node sT row stride f16: 128+8
#define EGRID 512         // persistent edge blocks (2 per CU)

typedef _Float16 f16;
typedef __attribute__((ext_vector_type(2))) _Float16 f16x2;
typedef __attribute__((ext_vector_type(4))) _Float16 f16x4;
typedef __attribute__((ext_vector_type(8))) _Float16 f16x8;
typedef __attribute__((ext_vector_type(4))) float    f32x4;
typedef __attribute__((ext_vector_type(4))) unsigned int u32x4;

__device__ __forceinline__ f32x4 mfma16(f16x8 a, f16x8 b, f32x4 c) {
    return __builtin_amdgcn_mfma_f32_16x16x32_f16(a, b, c, 0, 0, 0);
}
__device__ __forceinline__ f16x8 cvt8(const float* p) {
    const float4 a0 = *(const float4*)p;
    const float4 a1 = *(const float4*)(p + 4);
    f16x8 v;
    v[0] = (f16)a0.x; v[1] = (f16)a0.y; v[2] = (f16)a0.z; v[3] = (f16)a0.w;
    v[4] = (f16)a1.x; v[5] = (f16)a1.y; v[6] = (f16)a1.z; v[7] = (f16)a1.w;
    return v;
}

// ---------------------------------------------------------------- utility
__global__ __launch_bounds__(256) void zero_f32(float4* p, long n4) {
    long i = (long)blockIdx.x * blockDim.x + threadIdx.x;
    const long stride = (long)gridDim.x * blockDim.x;
    const float4 z = make_float4(0.f, 0.f, 0.f, 0.f);
    for (; i < n4; i += stride) p[i] = z;
}
__global__ __launch_bounds__(256) void zero_i32(int* p, int n) {
    int i = blockIdx.x * blockDim.x + threadIdx.x;
    if (i < n) p[i] = 0;
}
__global__ __launch_bounds__(256)
void cvt_f16_kernel(const float* __restrict__ x, f16* __restrict__ y, long n8) {
    long i = blockIdx.x * 256 + threadIdx.x;
    const long stride = (long)gridDim.x * 256;
    for (; i < n8; i += stride) *(f16x8*)(y + i * 8) = cvt8(x + i * 8);
}
// pack all 4 weight mats -> frag order [kt][w][lane][8] f16  (w = hid16 slice 0..7)
// blocks: 0..17 ew1(KT9), 18..25 ew2(KT4), 26..41 nw1(KT8), 42..49 nw2(KT4)
__global__ __launch_bounds__(256)
void pack_all_kernel(const float* __restrict__ ew1, const float* __restrict__ ew2,
                     const float* __restrict__ nw1, const float* __restrict__ nw2,
                     f16* __restrict__ w1p, f16* __restrict__ w2p,
                     f16* __restrict__ n1p, f16* __restrict__ n2p)
{
    const int b = blockIdx.x;
    const float* w; f16* wp; int base;
    if (b < 18)      { w = ew1; wp = w1p; base = b; }
    else if (b < 26) { w = ew2; wp = w2p; base = b - 18; }
    else if (b < 42) { w = nw1; wp = n1p; base = b - 26; }
    else             { w = nw2; wp = n2p; base = b - 42; }
    const int idx = base * 256 + threadIdx.x;
    const int l  = idx & 63;
    const int fr = idx >> 6;
    const int wi = fr & 7, kt = fr >> 3;
    const int lii = l & 15, qq = l >> 4;
    const float* p = w + (size_t)(32 * kt + 8 * qq) * HD + 16 * wi + lii;
    f16x8 v;
#pragma unroll
    for (int e2 = 0; e2 < 8; ++e2) v[e2] = (f16)p[(size_t)e2 * HD];
    *(f16x8*)(wp + (size_t)idx * 8) = v;
}

// ---------------------------------------------------------------- CSR build
__global__ __launch_bounds__(256)
void hist_kernel(const int* __restrict__ eidx, int* __restrict__ rank,
                 int* __restrict__ cnt, int E) {
    int e = blockIdx.x * 256 + threadIdx.x;
    if (e < E) rank[e] = atomicAdd(&cnt[eidx[E + e]], 1);
}
__global__ __launch_bounds__(1024)
void scan_kernel(const int* __restrict__ cnt, int* __restrict__ rs, int N) {
    __shared__ int wsum[16];
    __shared__ int s_carry;
    const int t = threadIdx.x, lane = t & 63, wid = t >> 6;
    if (t == 0) s_carry = 0;
    __syncthreads();
    for (int base = 0; base < N; base += 1024) {
        const int i = base + t;
        const int v = (i < N) ? cnt[i] : 0;
        int incl = v;
#pragma unroll
        for (int off = 1; off < 64; off <<= 1) {
            int u = __shfl_up(incl, off, 64);
            if (lane >= off) incl += u;
        }
        if (lane == 63) wsum[wid] = incl;
        __syncthreads();
        if (t == 0) {
            int s = 0;
#pragma unroll
            for (int w = 0; w < 16; ++w) { int x = wsum[w]; wsum[w] = s; s += x; }
        }
        __syncthreads();
        const int carry = s_carry;
        if (i < N) rs[i] = carry + wsum[wid] + incl - v;
        __syncthreads();
        if (t == 1023) s_carry = carry + wsum[15] + incl;
        __syncthreads();
    }
    if (threadIdx.x == 0) rs[N] = s_carry;
}
__global__ __launch_bounds__(256)
void pos_kernel(const int* __restrict__ eidx, const int* __restrict__ rs,
                int* __restrict__ pos, int E) {
    int e = blockIdx.x * 256 + threadIdx.x;
    if (e < E) pos[e] = rs[eidx[E + e]] + pos[e];
}

// ---------------------------------------------------------------- edges
// 512 threads, 8 waves; wave w owns hid slice [16w,16w+16); weights in regs.
// XOR-swizzled LDS: chunk' = chunk ^ (row&7).  Persistent grid, prefetch-by-1.
// MODE 0: fp32 atomic scatter into agg.  MODE 1: f16 row store at m[pos[e]].
template <int MODE>
__global__ __launch_bounds__(512, 4)
void edge_kernel(const f16*   __restrict__ h16,
                 const int*   __restrict__ eidx,
                 const float* __restrict__ ea,
                 const f16*   __restrict__ w1p,   // packed frags, KT=9
                 const float* __restrict__ b1,
                 const f16*   __restrict__ w2p,   // packed frags, KT=4
                 const float* __restrict__ b2,
                 void*        __restrict__ aggm,  // MODE0: float* ; MODE1: f16*
                 const int*   __restrict__ pos,
                 int E, int ntiles)
{
    __shared__ __align__(16) f16 sA[BME * 320];   // 40960 B (40 chunks/row, 36 used)
    __shared__ __align__(16) f16 sT[BME * 128];   // 16384 B (16 chunks/row)
    __shared__ int sIdx[2][BME];

    const int t  = threadIdx.x;
    const int l  = t & 63;
    const int wv = t >> 6;            // 0..7
    const int li = l & 15;
    const int q  = l >> 4;            // 0..3
    const int lm = l & 7;             // == li & 7 == row&7 for rows 16*et+li
    const int r  = t >> 3;            // staging row 0..63
    const int q8 = t & 7;             // staging chunk id within row

    // ---- weights -> registers, once per block (52 VGPR) ----
    f16x8 A1[9], A2[4];
#pragma unroll
    for (int kt = 0; kt < 9; ++kt)
        A1[kt] = *(const f16x8*)(w1p + ((size_t)(kt * 8 + wv) * 64 + l) * 8);
#pragma unroll
    for (int kt = 0; kt < 4; ++kt)
        A2[kt] = *(const f16x8*)(w2p + ((size_t)(kt * 8 + wv) * 64 + l) * 8);

    // ---- prefetch: tile row-data -> registers ----
    f16x8 d[4];
    f16x8 d4;                          // ea chunk (q8<4 only)
    int   psr = 0;
    auto prefetch = [&](int tile) {
        const int ec  = min(tile * BME + r, E - 1);
        const int src = eidx[ec];
        const int dst = eidx[E + ec];
        psr = (MODE == 0) ? dst : pos[ec];
        const f16* hs = h16 + (size_t)src * HD;
        const f16* hd = h16 + (size_t)dst * HD;
#pragma unroll
        for (int i = 0; i < 4; ++i) {
            const int c = (q8 + 8 * i) * 8;        // < 256 always
            d[i] = (c < HD) ? *(const f16x8*)(hs + c)
                            : *(const f16x8*)(hd + (c - HD));
        }
        if (q8 < 4) d4 = cvt8(ea + (size_t)ec * ED + q8 * 8);
    };

    int tb = blockIdx.x;
    if (tb < ntiles) prefetch(tb);
    int par = 0;

    for (; tb < ntiles; tb += gridDim.x, par ^= 1) {
        // ---- stage regs -> sA (swizzled) ----
        {
            f16* row = sA + r * 320;
            const int sw = r & 7;
#pragma unroll
            for (int i = 0; i < 4; ++i) {
                const int ch = q8 + 8 * i;
                *(f16x8*)(row + ((ch ^ sw) * 8)) = d[i];
            }
            if (q8 < 4)
                *(f16x8*)(row + (((q8 + 32) ^ sw) * 8)) = d4;
            if (q8 == 0) sIdx[par][r] = psr;
        }
        __syncthreads();                                  // S1: sA ready

        const int nt = tb + (int)gridDim.x;
        if (nt < ntiles) prefetch(nt);                    // hide under GEMMs

        // ---- GEMM1: K=288 ----
        f32x4 acc[4];
#pragma unroll
        for (int j = 0; j < 4; ++j) acc[j] = (f32x4){0.f, 0.f, 0.f, 0.f};
#pragma unroll
        for (int kt = 0; kt < 9; ++kt) {
#pragma unroll
            for (int et = 0; et < 4; ++et) {
                const f16x8 b = *(const f16x8*)(sA + (16 * et + li) * 320
                                                + (((4 * kt + q) ^ lm) * 8));
                acc[et] = mfma16(A1[kt], b, acc[et]);
            }
        }

        // ---- epilogue1: +b1, relu -> sT (swizzled) ----
        {
            const int hidb = 16 * wv + 4 * q;
            const float4 bb = *(const float4*)(b1 + hidb);
            const int chT = hidb >> 3;
            const int off = hidb & 7;                     // 0 or 4
#pragma unroll
            for (int et = 0; et < 4; ++et) {
                const f32x4 v = acc[et];
                float x0 = fmaxf(v[0] + bb.x, 0.f), x1 = fmaxf(v[1] + bb.y, 0.f);
                float x2 = fmaxf(v[2] + bb.z, 0.f), x3 = fmaxf(v[3] + bb.w, 0.f);
                f16x4 o; o[0] = (f16)x0; o[1] = (f16)x1; o[2] = (f16)x2; o[3] = (f16)x3;
                *(f16x4*)(sT + (16 * et + li) * 128 + ((chT ^ lm) * 8) + off) = o;
            }
        }
        __syncthreads();                                  // S2: sT ready

        // ---- GEMM2: K=128 ----
        f32x4 acc2[4];
#pragma unroll
        for (int j = 0; j < 4; ++j) acc2[j] = (f32x4){0.f, 0.f, 0.f, 0.f};
#pragma unroll
        for (int kt = 0; kt < 4; ++kt) {
#pragma unroll
            for (int et = 0; et < 4; ++et) {
                const f16x8 b = *(const f16x8*)(sT + (16 * et + li) * 128
                                                + (((4 * kt + q) ^ lm) * 8));
                acc2[et] = mfma16(A2[kt], b, acc2[et]);
            }
        }

        if (MODE == 0) {
            float* agg = (float*)aggm;
            const int hidb = 16 * wv + 4 * q;
            const float4 bb = *(const float4*)(b2 + hidb);
#pragma unroll
            for (int et = 0; et < 4; ++et) {
                const int edge = 16 * et + li;
                if (tb * BME + edge < E) {
                    float* p = agg + (size_t)sIdx[par][edge] * HD + hidb;
                    const f32x4 v = acc2[et];
                    atomicAdd(p + 0, v[0] + bb.x);
                    atomicAdd(p + 1, v[1] + bb.y);
                    atomicAdd(p + 2, v[2] + bb.z);
                    atomicAdd(p + 3, v[3] + bb.w);
                }
            }
            __syncthreads();
        } else {
            __syncthreads();                              // S3: GEMM2 done reading sT
            {
                const int hidb = 16 * wv + 4 * q;
                const float4 bb = *(const float4*)(b2 + hidb);
                const int chT = hidb >> 3;
                const int off = hidb & 7;
#pragma unroll
                for (int et = 0; et < 4; ++et) {
                    const f32x4 v = acc2[et];
                    f16x4 o;
                    o[0] = (f16)(v[0] + bb.x); o[1] = (f16)(v[1] + bb.y);
                    o[2] = (f16)(v[2] + bb.z); o[3] = (f16)(v[3] + bb.w);
                    *(f16x4*)(sT + (16 * et + li) * 128 + ((chT ^ lm) * 8) + off) = o;
                }
            }
            __syncthreads();                              // S4: result tile ready
            f16* m = (f16*)aggm;
#pragma unroll
            for (int i = 0; i < 2; ++i) {
                const int idx  = t + i * 512;             // 0..1023
                const int row2 = idx >> 4;                // 0..63
                const int c    = idx & 15;
                if (tb * BME + row2 < E) {
                    const f16x8 v = *(const f16x8*)(sT + row2 * 128
                                                    + ((c ^ (row2 & 7)) * 8));
                    __builtin_nontemporal_store(*(const u32x4*)&v,
                        (u32x4*)(m + (size_t)sIdx[par][row2] * HD + c * 8));
                }
            }
        }
    }
}

// ---------------------------------------------------------------- gather
__global__ __launch_bounds__(256)
void gather_kernel(const f16* __restrict__ m, const int* __restrict__ rs,
                   f16* __restrict__ aggb, int N)
{
    const int n = blockIdx.x * 4 + (threadIdx.x >> 6);
    if (n >= N) return;
    const int lane = threadIdx.x & 63;
    const int s = rs[n], e = rs[n + 1];
    const f16* base = m + (size_t)s * HD + lane * 2;
    const int cnt = e - s;
    float a0 = 0.f, b0 = 0.f, a1 = 0.f, b1 = 0.f;
    int j = 0;
    for (; j + 2 <= cnt; j += 2) {
        const unsigned int uu = __builtin_nontemporal_load(
            (const unsigned int*)(base + (size_t)j * HD));
        const unsigned int vv = __builtin_nontemporal_load(
            (const unsigned int*)(base + (size_t)(j + 1) * HD));
        const f16x2 u = *(const f16x2*)&uu;
        const f16x2 v = *(const f16x2*)&vv;
        a0 += (float)u[0]; b0 += (float)u[1];
        a1 += (float)v[0]; b1 += (float)v[1];
    }
    if (j < cnt) {
        const unsigned int uu = __builtin_nontemporal_load(
            (const unsigned int*)(base + (size_t)j * HD));
        const f16x2 u = *(const f16x2*)&uu;
        a0 += (float)u[0]; b0 += (float)u[1];
    }
    f16x2 rr; rr[0] = (f16)(a0 + a1); rr[1] = (f16)(b0 + b1);
    *(f16x2*)(aggb + (size_t)n * HD + lane * 2) = rr;
}

// ---------------------------------------------------------------- nodes
// 256 threads; weights in registers per wave-pair layout (w = wv*2 + ht).
// CSR=1: agg half from dense f16 aggb.  CSR=0: from dense f32 aggf.
template <int CSR>
__global__ __launch_bounds__(256, 2)
void node_kernel(const f16*   __restrict__ h16,
                 const float* __restrict__ h,      // f32 residual
                 const f16*   __restrict__ aggb,
                 const float* __restrict__ aggf,
                 const f16*   __restrict__ w1p,    // KT=8
                 const float* __restrict__ b1,
                 const f16*   __restrict__ w2p,    // KT=4
                 const float* __restrict__ b2,
                 const float* __restrict__ gamma,
                 const float* __restrict__ beta,
                 float*       __restrict__ out,
                 int N)
{
    __shared__ __align__(16) f16 sA[BMN * PAD_N];  // 67584 B; sT & sX alias
    __shared__ float sMV[2 * BMN];

    const int t  = threadIdx.x;
    const int l  = t & 63;
    const int wv = t >> 6;
    const int li = l & 15;
    const int q  = l >> 4;
    const int nbase = blockIdx.x * BMN;

    // ---- stage sA[node][0..256) = [h16 | agg] : 128 f16 per thread ----
    {
        const int r = t >> 1, half = t & 1;
        const int node = min(nbase + r, N - 1);
        f16* rowp = sA + r * PAD_N + half * HD;
        if (half == 0) {
            const f16* src = h16 + (size_t)node * HD;
#pragma unroll
            for (int i = 0; i < 16; ++i)
                *(f16x8*)(rowp + i * 8) = *(const f16x8*)(src + i * 8);
        } else if (CSR) {
            const f16* src = aggb + (size_t)node * HD;
#pragma unroll
            for (int i = 0; i < 16; ++i)
                *(f16x8*)(rowp + i * 8) = *(const f16x8*)(src + i * 8);
        } else {
            const float* src = aggf + (size_t)node * HD;
#pragma unroll
            for (int i = 0; i < 16; ++i)
                *(f16x8*)(rowp + i * 8) = cvt8(src + i * 8);
        }
    }

    // ---- A1 -> registers (overlaps staging) ----
    f16x8 A1[2][8];
#pragma unroll
    for (int ht = 0; ht < 2; ++ht)
#pragma unroll
        for (int kt = 0; kt < 8; ++kt)
            A1[ht][kt] = *(const f16x8*)(w1p + ((size_t)(kt * 8 + wv * 2 + ht) * 64 + l) * 8);
    __syncthreads();                                  // S1

    // ---- GEMM1: K=256 ----
    f32x4 acc[2][8];
#pragma unroll
    for (int i = 0; i < 2; ++i)
#pragma unroll
        for (int j = 0; j < 8; ++j) acc[i][j] = (f32x4){0.f, 0.f, 0.f, 0.f};
#pragma unroll
    for (int kt = 0; kt < 8; ++kt) {
#pragma unroll
        for (int et = 0; et < 8; ++et) {
            const f16x8 b = *(const f16x8*)(sA + (16 * et + li) * PAD_N + 32 * kt + 8 * q);
            acc[0][et] = mfma16(A1[0][kt], b, acc[0][et]);
            acc[1][et] = mfma16(A1[1][kt], b, acc[1][et]);
        }
    }
    __syncthreads();                                  // S2: sA reads done (alias!)

    // ---- A2 -> registers ----
    f16x8 A2[2][4];
#pragma unroll
    for (int ht = 0; ht < 2; ++ht)
#pragma unroll
        for (int kt = 0; kt < 4; ++kt)
            A2[ht][kt] = *(const f16x8*)(w2p + ((size_t)(kt * 8 + wv * 2 + ht) * 64 + l) * 8);

    // ---- epilogue1: +b1, relu -> sT (aliases sA) ----
    f16* sT = sA;
#pragma unroll
    for (int ht = 0; ht < 2; ++ht) {
        const int hidb = 32 * wv + 16 * ht + 4 * q;
        const float4 bb = *(const float4*)(b1 + hidb);
#pragma unroll
        for (int et = 0; et < 8; ++et) {
            const f32x4 v = acc[ht][et];
            float x0 = fmaxf(v[0] + bb.x, 0.f), x1 = fmaxf(v[1] + bb.y, 0.f);
            float x2 = fmaxf(v[2] + bb.z, 0.f), x3 = fmaxf(v[3] + bb.w, 0.f);
            f16x4 o; o[0] = (f16)x0; o[1] = (f16)x1; o[2] = (f16)x2; o[3] = (f16)x3;
            *(f16x4*)(sT + (16 * et + li) * PAD_T + hidb) = o;
        }
    }
    __syncthreads();                                  // S3: sT ready

    // ---- GEMM2: K=128 ----
    f32x4 acc2[2][8];
#pragma unroll
    for (int i = 0; i < 2; ++i)
#pragma unroll
        for (int j = 0; j < 8; ++j) acc2[i][j] = (f32x4){0.f, 0.f, 0.f, 0.f};
#pragma unroll
    for (int kt = 0; kt < 4; ++kt) {
#pragma unroll
        for (int et = 0; et < 8; ++et) {
            const f16x8 b = *(const f16x8*)(sT + (16 * et + li) * PAD_T + 32 * kt + 8 * q);
            acc2[0][et] = mfma16(A2[0][kt], b, acc2[0][et]);
            acc2[1][et] = mfma16(A2[1][kt], b, acc2[1][et]);
        }
    }
    __syncthreads();                                  // S4: sT reads done

    // ---- epilogue2: x = upd + b2 + h -> sX f32 (aliases sA) ----
    float* sX = (float*)sA;            // stride 132 f32
#pragma unroll
    for (int ht = 0; ht < 2; ++ht) {
        const int hidb = 32 * wv + 16 * ht + 4 * q;
        const float4 bb = *(const float4*)(b2 + hidb);
#pragma unroll
        for (int et = 0; et < 8; ++et) {
            const int node = 16 * et + li;
            const int nc   = min(nbase + node, N - 1);
            const float4 hv = *(const float4*)(h + (size_t)nc * HD + hidb);
            const f32x4 v = acc2[ht][et];
            f32x4 x;
            x[0] = v[0] + bb.x + hv.x;
            x[1] = v[1] + bb.y + hv.y;
            x[2] = v[2] + bb.z + hv.z;
            x[3] = v[3] + bb.w + hv.w;
            *(f32x4*)(sX + (size_t)node * 132 + hidb) = x;
        }
    }
    __syncthreads();                                  // S5

    // ---- LayerNorm ----
    {
        const int node  = t >> 1;
        const int half2 = t & 1;
        const float* px = sX + node * 132 + half2 * 64;
        float s = 0.f, sq = 0.f;
#pragma unroll
        for (int i = 0; i < 16; ++i) {
            const float4 v = *(const float4*)(px + i * 4);
            s  += v.x + v.y + v.z + v.w;
            sq += v.x * v.x + v.y * v.y + v.z * v.z + v.w * v.w;
        }
        s  += __shfl_xor(s, 1);
        sq += __shfl_xor(sq, 1);
        if (!half2) {
            const float mean = s * (1.f / HD);
            const float var  = sq * (1.f / HD) - mean * mean;
            sMV[node]       = mean;
            sMV[BMN + node] = rsqrtf(var + 1e-5f);
        }
    }
    __syncthreads();                                  // S6

#pragma unroll
    for (int i = 0; i < 16; ++i) {
        const int idx  = t + i * 256;
        const int node = idx >> 5;
        const int c4   = (idx & 31) * 4;
        if (nbase + node < N) {
            const float4 xv = *(const float4*)(sX + node * 132 + c4);
            const float4 g4 = *(const float4*)(gamma + c4);
            const float4 b4 = *(const float4*)(beta + c4);
            const float mean = sMV[node];
            const float rstd = sMV[BMN + node];
            float4 o;
            o.x = (xv.x - mean) * rstd * g4.x + b4.x;
            o.y = (xv.y - mean) * rstd * g4.y + b4.y;
            o.z = (xv.z - mean) * rstd * g4.z + b4.z;
            o.w = (xv.w - mean) * rstd * g4.w + b4.w;
            *(float4*)(out + (size_t)(nbase + node) * HD + c4) = o;
        }
    }
}

// ---------------------------------------------------------------- launch
extern "C" void kernel_launch(void* const* d_in, const int* in_sizes, int n_in,
                              void* d_out, int out_size, void* d_ws, size_t ws_size,
                              hipStream_t stream)
{
    const float* h     = (const float*)d_in[0];
    const int*   eidx  = (const int*)  d_in[1];
    const float* ea    = (const float*)d_in[2];
    const float* ew1   = (const float*)d_in[3];
    const float* eb1   = (const float*)d_in[4];
    const float* ew2   = (const float*)d_in[5];
    const float* eb2   = (const float*)d_in[6];
    const float* nw1   = (const float*)d_in[7];
    const float* nb1   = (const float*)d_in[8];
    const float* nw2   = (const float*)d_in[9];
    const float* nb2   = (const float*)d_in[10];
    const float* gamma = (const float*)d_in[11];
    const float* beta  = (const float*)d_in[12];
    float* out = (float*)d_out;

    const int N = in_sizes[0] / HD;
    const int E = in_sizes[1] / 2;
    const int ntiles = (E + BME - 1) / BME;

    size_t off = 0;
    auto alloc = [&](size_t bytes) {
        size_t o = off; off += (bytes + 255) & ~(size_t)255; return o;
    };
    const size_t o_m    = alloc((size_t)E * HD * sizeof(f16));
    const size_t o_agb  = alloc((size_t)N * HD * sizeof(f16));
    const size_t o_h16  = alloc((size_t)N * HD * sizeof(f16));
    const size_t o_pos  = alloc((size_t)E * sizeof(int));
    const size_t o_rs   = alloc((size_t)(N + 1) * sizeof(int));
    const size_t o_cnt  = alloc((size_t)N * sizeof(int));
    const size_t o_w1p  = alloc((size_t)9 * 8 * 64 * 8 * sizeof(f16));
    const size_t o_w2p  = alloc((size_t)4 * 8 * 64 * 8 * sizeof(f16));
    const size_t o_n1p  = alloc((size_t)8 * 8 * 64 * 8 * sizeof(f16));
    const size_t o_n2p  = alloc((size_t)4 * 8 * 64 * 8 * sizeof(f16));
    const bool csr = (off <= ws_size);
    char* ws = (char*)d_ws;

    if (csr) {
        f16* mb   = (f16*)(ws + o_m);
        f16* aggb = (f16*)(ws + o_agb);
        f16* h16  = (f16*)(ws + o_h16);
        int* pos  = (int*)(ws + o_pos);
        int* rs   = (int*)(ws + o_rs);
        int* cnt  = (int*)(ws + o_cnt);
        f16* w1p  = (f16*)(ws + o_w1p);
        f16* w2p  = (f16*)(ws + o_w2p);
        f16* n1p  = (f16*)(ws + o_n1p);
        f16* n2p  = (f16*)(ws + o_n2p);

        zero_i32<<<(N + 255) / 256, 256, 0, stream>>>(cnt, N);
        hist_kernel<<<(E + 255) / 256, 256, 0, stream>>>(eidx, pos, cnt, E);
        scan_kernel<<<1, 1024, 0, stream>>>(cnt, rs, N);
        pos_kernel<<<(E + 255) / 256, 256, 0, stream>>>(eidx, rs, pos, E);
        cvt_f16_kernel<<<2048, 256, 0, stream>>>(h, h16, (long)N * HD / 8);
        pack_all_kernel<<<50, 256, 0, stream>>>(ew1, ew2, nw1, nw2, w1p, w2p, n1p, n2p);
        edge_kernel<1><<<EGRID, 512, 0, stream>>>(
            h16, eidx, ea, w1p, eb1, w2p, eb2, (void*)mb, pos, E, ntiles);
        gather_kernel<<<(N + 3) / 4, 256, 0, stream>>>(mb, rs, aggb, N);
        node_kernel<1><<<(N + BMN - 1) / BMN, 256, 0, stream>>>(
            h16, h, aggb, nullptr, n1p, nb1, n2p, nb2, gamma, beta, out, N);
    } else {
        // fallback: dense f32 atomic aggregation
        size_t foff = 0;
        auto falloc = [&](size_t bytes) {
            size_t o = foff; foff += (bytes + 255) & ~(size_t)255; return o;
        };
        float* agg = (float*)(ws + falloc((size_t)N * HD * sizeof(float)));
        f16*   h16 = (f16*)  (ws + falloc((size_t)N * HD * sizeof(f16)));
        f16*   w1p = (f16*)  (ws + falloc((size_t)9 * 8 * 64 * 8 * sizeof(f16)));
        f16*   w2p = (f16*)  (ws + falloc((size_t)4 * 8 * 64 * 8 * sizeof(f16)));
        f16*   n1p = (f16*)  (ws + falloc((size_t)8 * 8 * 64 * 8 * sizeof(f16)));
        f16*   n2p = (f16*)  (ws + falloc((size_t)4 * 8 * 64 * 8 * sizeof(f16)));

        zero_f32<<<1024, 256, 0, stream>>>((float4*)agg, (long)N * HD / 4);
        cvt_f16_kernel<<<2048, 256, 0, stream>>>(h, h16, (long)N * HD / 8);
        pack_all_kernel<<<50, 256, 0, stream>>>(ew1, ew2, nw1, nw2, w1p, w2p, n1p, n2p);
        edge_kernel<0><<<EGRID, 512, 0, stream>>>(
            h16, eidx, ea, w1p, eb1, w2p, eb2, (void*)agg, nullptr, E, ntiles);
        node_kernel<0><<<(N + BMN - 1) / BMN, 256, 0, stream>>>(
            h16, h, nullptr, agg, n1p, nb1, n2p, nb2, gamma, beta, out, N);
    }
}

// Round 10
// 281.362 us; speedup vs baseline: 4.8738x; 1.0011x over previous
//
#include <hip/hip_runtime.h>
#include <cstdint>

#define HD 128
#define ED 32
#define BME 64            // edges per tile (edge kernel)
#define BMN 128           // nodes per block (node kernel)
#define PAD_N 264         // node sA row stride f16: 256+8
#define PAD_T 136         // node sT row stride f16: 128+8
#define EGRID 512         // persistent edge blocks (2 per CU)

typedef _Float16 f16;
typedef __attribute__((ext_vector_type(2))) _Float16 f16x2;
typedef __attribute__((ext_vector_type(4))) _Float16 f16x4;
typedef __attribute__((ext_vector_type(8))) _Float16 f16x8;
typedef __attribute__((ext_vector_type(4))) float    f32x4;
typedef __attribute__((ext_vector_type(4))) unsigned int u32x4;

__device__ __forceinline__ f32x4 mfma16(f16x8 a, f16x8 b, f32x4 c) {
    return __builtin_amdgcn_mfma_f32_16x16x32_f16(a, b, c, 0, 0, 0);
}
__device__ __forceinline__ f16x8 cvt8(const float* p) {
    const float4 a0 = *(const float4*)p;
    const float4 a1 = *(const float4*)(p + 4);
    f16x8 v;
    v[0] = (f16)a0.x; v[1] = (f16)a0.y; v[2] = (f16)a0.z; v[3] = (f16)a0.w;
    v[4] = (f16)a1.x; v[5] = (f16)a1.y; v[6] = (f16)a1.z; v[7] = (f16)a1.w;
    return v;
}
// barrier that drains LDS only — vmem loads/stores stay in flight (T4)
__device__ __forceinline__ void barrier_lds() {
    asm volatile("s_waitcnt lgkmcnt(0)" ::: "memory");
    __builtin_amdgcn_s_barrier();
    __builtin_amdgcn_sched_barrier(0);
}

// ---------------------------------------------------------------- utility
__global__ __launch_bounds__(256) void zero_f32(float4* p, long n4) {
    long i = (long)blockIdx.x * blockDim.x + threadIdx.x;
    const long stride = (long)gridDim.x * blockDim.x;
    const float4 z = make_float4(0.f, 0.f, 0.f, 0.f);
    for (; i < n4; i += stride) p[i] = z;
}
__global__ __launch_bounds__(256) void zero_i32(int* p, int n) {
    int i = blockIdx.x * blockDim.x + threadIdx.x;
    if (i < n) p[i] = 0;
}
__global__ __launch_bounds__(256)
void cvt_f16_kernel(const float* __restrict__ x, f16* __restrict__ y, long n8) {
    long i = blockIdx.x * 256 + threadIdx.x;
    const long stride = (long)gridDim.x * 256;
    for (; i < n8; i += stride) *(f16x8*)(y + i * 8) = cvt8(x + i * 8);
}
// pack all 4 weight mats -> frag order [kt][w][lane][8] f16  (w = hid16 slice 0..7)
__global__ __launch_bounds__(256)
void pack_all_kernel(const float* __restrict__ ew1, const float* __restrict__ ew2,
                     const float* __restrict__ nw1, const float* __restrict__ nw2,
                     f16* __restrict__ w1p, f16* __restrict__ w2p,
                     f16* __restrict__ n1p, f16* __restrict__ n2p)
{
    const int b = blockIdx.x;
    const float* w; f16* wp; int base;
    if (b < 18)      { w = ew1; wp = w1p; base = b; }
    else if (b < 26) { w = ew2; wp = w2p; base = b - 18; }
    else if (b < 42) { w = nw1; wp = n1p; base = b - 26; }
    else             { w = nw2; wp = n2p; base = b - 42; }
    const int idx = base * 256 + threadIdx.x;
    const int l  = idx & 63;
    const int fr = idx >> 6;
    const int wi = fr & 7, kt = fr >> 3;
    const int lii = l & 15, qq = l >> 4;
    const float* p = w + (size_t)(32 * kt + 8 * qq) * HD + 16 * wi + lii;
    f16x8 v;
#pragma unroll
    for (int e2 = 0; e2 < 8; ++e2) v[e2] = (f16)p[(size_t)e2 * HD];
    *(f16x8*)(wp + (size_t)idx * 8) = v;
}

// ---------------------------------------------------------------- CSR build
__global__ __launch_bounds__(256)
void hist_kernel(const int* __restrict__ eidx, int* __restrict__ rank,
                 int* __restrict__ cnt, int E) {
    int e = blockIdx.x * 256 + threadIdx.x;
    if (e < E) rank[e] = atomicAdd(&cnt[eidx[E + e]], 1);
}
__global__ __launch_bounds__(1024)
void scan_kernel(const int* __restrict__ cnt, int* __restrict__ rs, int N) {
    __shared__ int wsum[16];
    __shared__ int s_carry;
    const int t = threadIdx.x, lane = t & 63, wid = t >> 6;
    if (t == 0) s_carry = 0;
    __syncthreads();
    for (int base = 0; base < N; base += 1024) {
        const int i = base + t;
        const int v = (i < N) ? cnt[i] : 0;
        int incl = v;
#pragma unroll
        for (int off = 1; off < 64; off <<= 1) {
            int u = __shfl_up(incl, off, 64);
            if (lane >= off) incl += u;
        }
        if (lane == 63) wsum[wid] = incl;
        __syncthreads();
        if (t == 0) {
            int s = 0;
#pragma unroll
            for (int w = 0; w < 16; ++w) { int x = wsum[w]; wsum[w] = s; s += x; }
        }
        __syncthreads();
        const int carry = s_carry;
        if (i < N) rs[i] = carry + wsum[wid] + incl - v;
        __syncthreads();
        if (t == 1023) s_carry = carry + wsum[15] + incl;
        __syncthreads();
    }
    if (threadIdx.x == 0) rs[N] = s_carry;
}
__global__ __launch_bounds__(256)
void pos_kernel(const int* __restrict__ eidx, const int* __restrict__ rs,
                int* __restrict__ pos, int E) {
    int e = blockIdx.x * 256 + threadIdx.x;
    if (e < E) pos[e] = rs[eidx[E + e]] + pos[e];
}

// ---------------------------------------------------------------- edges
// 512 threads, 8 waves; wave w owns hid slice [16w,16w+16).
// lgkm-only barriers: vmem (gather prefetch + weight streams) never drained.
// MODE 0: fp32 atomic scatter into agg.  MODE 1: f16 row store at m[pos[e]].
template <int MODE>
__global__ __launch_bounds__(512, 4)
void edge_kernel(const f16*   __restrict__ h16,
                 const int*   __restrict__ eidx,
                 const float* __restrict__ ea,
                 const f16*   __restrict__ w1p,   // packed frags, KT=9
                 const float* __restrict__ b1,
                 const f16*   __restrict__ w2p,   // packed frags, KT=4
                 const float* __restrict__ b2,
                 void*        __restrict__ aggm,  // MODE0: float* ; MODE1: f16*
                 const int*   __restrict__ pos,
                 int E, int ntiles)
{
    __shared__ __align__(16) f16 sA[BME * 320];   // 40960 B (40 chunks/row, 36 used)
    __shared__ __align__(16) f16 sT[BME * 128];   // 16384 B (16 chunks/row)
    __shared__ int sIdx[2][BME];

    const int t  = threadIdx.x;
    const int l  = t & 63;
    const int wv = t >> 6;            // 0..7
    const int li = l & 15;
    const int q  = l >> 4;            // 0..3
    const int lm = l & 7;             // row&7 for rows 16*et+li
    const int r  = t >> 3;            // staging row 0..63
    const int q8 = t & 7;             // staging chunk id within row

    // ---- weights -> registers (compiler may stream; loads float freely now) ----
    f16x8 A1[9], A2[4];
#pragma unroll
    for (int kt = 0; kt < 9; ++kt)
        A1[kt] = *(const f16x8*)(w1p + ((size_t)(kt * 8 + wv) * 64 + l) * 8);
#pragma unroll
    for (int kt = 0; kt < 4; ++kt)
        A2[kt] = *(const f16x8*)(w2p + ((size_t)(kt * 8 + wv) * 64 + l) * 8);

    // ---- prefetch: tile row-data -> registers ----
    f16x8 d[4];
    f16x8 d4;                          // ea chunk (q8<4 only)
    int   psr = 0;
    auto prefetch = [&](int tile) {
        const int ec  = min(tile * BME + r, E - 1);
        const int src = eidx[ec];
        const int dst = eidx[E + ec];
        psr = (MODE == 0) ? dst : pos[ec];
        const f16* hs = h16 + (size_t)src * HD;
        const f16* hd = h16 + (size_t)dst * HD;
#pragma unroll
        for (int i = 0; i < 4; ++i) {
            const int c = (q8 + 8 * i) * 8;        // < 256 always
            d[i] = (c < HD) ? *(const f16x8*)(hs + c)
                            : *(const f16x8*)(hd + (c - HD));
        }
        if (q8 < 4) d4 = cvt8(ea + (size_t)ec * ED + q8 * 8);
    };

    int tb = blockIdx.x;
    if (tb < ntiles) prefetch(tb);
    int par = 0;

    for (; tb < ntiles; tb += gridDim.x, par ^= 1) {
        // ---- stage regs -> sA (swizzled) ----
        {
            f16* row = sA + r * 320;
            const int sw = r & 7;
#pragma unroll
            for (int i = 0; i < 4; ++i) {
                const int ch = q8 + 8 * i;
                *(f16x8*)(row + ((ch ^ sw) * 8)) = d[i];
            }
            if (q8 < 4)
                *(f16x8*)(row + (((q8 + 32) ^ sw) * 8)) = d4;
            if (q8 == 0) sIdx[par][r] = psr;
        }
        barrier_lds();                                    // S1: sA ready

        const int nt = tb + (int)gridDim.x;
        if (nt < ntiles) prefetch(nt);                    // floats across barriers

        // ---- GEMM1: K=288 ----
        f32x4 acc[4];
#pragma unroll
        for (int j = 0; j < 4; ++j) acc[j] = (f32x4){0.f, 0.f, 0.f, 0.f};
#pragma unroll
        for (int kt = 0; kt < 9; ++kt) {
#pragma unroll
            for (int et = 0; et < 4; ++et) {
                const f16x8 b = *(const f16x8*)(sA + (16 * et + li) * 320
                                                + (((4 * kt + q) ^ lm) * 8));
                acc[et] = mfma16(A1[kt], b, acc[et]);
            }
        }

        // ---- epilogue1: +b1, relu -> sT (swizzled) ----
        {
            const int hidb = 16 * wv + 4 * q;
            const float4 bb = *(const float4*)(b1 + hidb);
            const int chT = hidb >> 3;
            const int off = hidb & 7;                     // 0 or 4
#pragma unroll
            for (int et = 0; et < 4; ++et) {
                const f32x4 v = acc[et];
                float x0 = fmaxf(v[0] + bb.x, 0.f), x1 = fmaxf(v[1] + bb.y, 0.f);
                float x2 = fmaxf(v[2] + bb.z, 0.f), x3 = fmaxf(v[3] + bb.w, 0.f);
                f16x4 o; o[0] = (f16)x0; o[1] = (f16)x1; o[2] = (f16)x2; o[3] = (f16)x3;
                *(f16x4*)(sT + (16 * et + li) * 128 + ((chT ^ lm) * 8) + off) = o;
            }
        }
        barrier_lds();                                    // S2: sT ready

        // ---- GEMM2: K=128 ----
        f32x4 acc2[4];
#pragma unroll
        for (int j = 0; j < 4; ++j) acc2[j] = (f32x4){0.f, 0.f, 0.f, 0.f};
#pragma unroll
        for (int kt = 0; kt < 4; ++kt) {
#pragma unroll
            for (int et = 0; et < 4; ++et) {
                const f16x8 b = *(const f16x8*)(sT + (16 * et + li) * 128
                                                + (((4 * kt + q) ^ lm) * 8));
                acc2[et] = mfma16(A2[kt], b, acc2[et]);
            }
        }

        if (MODE == 0) {
            float* agg = (float*)aggm;
            const int hidb = 16 * wv + 4 * q;
            const float4 bb = *(const float4*)(b2 + hidb);
#pragma unroll
            for (int et = 0; et < 4; ++et) {
                const int edge = 16 * et + li;
                if (tb * BME + edge < E) {
                    float* p = agg + (size_t)sIdx[par][edge] * HD + hidb;
                    const f32x4 v = acc2[et];
                    atomicAdd(p + 0, v[0] + bb.x);
                    atomicAdd(p + 1, v[1] + bb.y);
                    atomicAdd(p + 2, v[2] + bb.z);
                    atomicAdd(p + 3, v[3] + bb.w);
                }
            }
            barrier_lds();
        } else {
            barrier_lds();                                // S3: GEMM2 done reading sT
            {
                const int hidb = 16 * wv + 4 * q;
                const float4 bb = *(const float4*)(b2 + hidb);
                const int chT = hidb >> 3;
                const int off = hidb & 7;
#pragma unroll
                for (int et = 0; et < 4; ++et) {
                    const f32x4 v = acc2[et];
                    f16x4 o;
                    o[0] = (f16)(v[0] + bb.x); o[1] = (f16)(v[1] + bb.y);
                    o[2] = (f16)(v[2] + bb.z); o[3] = (f16)(v[3] + bb.w);
                    *(f16x4*)(sT + (16 * et + li) * 128 + ((chT ^ lm) * 8) + off) = o;
                }
            }
            barrier_lds();                                // S4: result tile ready
            f16* m = (f16*)aggm;
#pragma unroll
            for (int i = 0; i < 2; ++i) {
                const int idx  = t + i * 512;             // 0..1023
                const int row2 = idx >> 4;                // 0..63
                const int c    = idx & 15;
                if (tb * BME + row2 < E) {
                    const f16x8 v = *(const f16x8*)(sT + row2 * 128
                                                    + ((c ^ (row2 & 7)) * 8));
                    __builtin_nontemporal_store(*(const u32x4*)&v,
                        (u32x4*)(m + (size_t)sIdx[par][row2] * HD + c * 8));
                }
            }
        }
    }
}

// ---------------------------------------------------------------- nodes
// Gather fused into staging: node n's CSR segment of m is contiguous; a block's
// 128 nodes cover a contiguous range of m -> coalesced streaming sum.
// CSR=1: agg = sum m[rs[n]..rs[n+1]).  CSR=0: agg from dense f32 aggf.
template <int CSR>
__global__ __launch_bounds__(256, 2)
void node_kernel(const f16*   __restrict__ h16,
                 const float* __restrict__ h,      // f32 residual
                 const f16*   __restrict__ m,
                 const int*   __restrict__ rs,
                 const float* __restrict__ aggf,
                 const f16*   __restrict__ w1p,    // KT=8
                 const float* __restrict__ b1,
                 const f16*   __restrict__ w2p,    // KT=4
                 const float* __restrict__ b2,
                 const float* __restrict__ gamma,
                 const float* __restrict__ beta,
                 float*       __restrict__ out,
                 int N)
{
    __shared__ __align__(16) f16 sA[BMN * PAD_N];  // 67584 B; sT & sX alias
    __shared__ float sMV[2 * BMN];

    const int t  = threadIdx.x;
    const int l  = t & 63;
    const int wv = t >> 6;
    const int li = l & 15;
    const int q  = l >> 4;
    const int nbase = blockIdx.x * BMN;

    // ---- stage sA[node][0..256) = [h16 | agg-sum] : 2 threads/node, 64 cols each
    {
        const int r = t >> 1, half = t & 1;
        const int node = min(nbase + r, N - 1);
        f16* rowp = sA + r * PAD_N;
        // h16 half: cols [64*half, 64*half+64)
        {
            const f16* srcp = h16 + (size_t)node * HD + half * 64;
#pragma unroll
            for (int i = 0; i < 8; ++i)
                *(f16x8*)(rowp + half * 64 + i * 8) = *(const f16x8*)(srcp + i * 8);
        }
        if (CSR) {
            const int s = rs[node], en = rs[node + 1];
            float ag[64];
#pragma unroll
            for (int i = 0; i < 64; ++i) ag[i] = 0.f;
            const f16* base = m + (size_t)s * HD + half * 64;
            for (int j = 0; j < en - s; ++j) {
                const f16* rp = base + (size_t)j * HD;
#pragma unroll
                for (int i = 0; i < 8; ++i) {
                    const f16x8 v = *(const f16x8*)(rp + i * 8);
#pragma unroll
                    for (int k2 = 0; k2 < 8; ++k2) ag[i * 8 + k2] += (float)v[k2];
                }
            }
#pragma unroll
            for (int i = 0; i < 8; ++i) {
                f16x8 o;
#pragma unroll
                for (int k2 = 0; k2 < 8; ++k2) o[k2] = (f16)ag[i * 8 + k2];
                *(f16x8*)(rowp + 128 + half * 64 + i * 8) = o;
            }
        } else {
            const float* srcp = aggf + (size_t)node * HD + half * 64;
#pragma unroll
            for (int i = 0; i < 8; ++i)
                *(f16x8*)(rowp + 128 + half * 64 + i * 8) = cvt8(srcp + i * 8);
        }
    }
    __syncthreads();                                  // S1

    // ---- A1 -> registers (after S1 to avoid pressure in gather loop) ----
    f16x8 A1[2][8];
#pragma unroll
    for (int ht = 0; ht < 2; ++ht)
#pragma unroll
        for (int kt = 0; kt < 8; ++kt)
            A1[ht][kt] = *(const f16x8*)(w1p + ((size_t)(kt * 8 + wv * 2 + ht) * 64 + l) * 8);

    // ---- GEMM1: K=256 ----
    f32x4 acc[2][8];
#pragma unroll
    for (int i = 0; i < 2; ++i)
#pragma unroll
        for (int j = 0; j < 8; ++j) acc[i][j] = (f32x4){0.f, 0.f, 0.f, 0.f};
#pragma unroll
    for (int kt = 0; kt < 8; ++kt) {
#pragma unroll
        for (int et = 0; et < 8; ++et) {
            const f16x8 b = *(const f16x8*)(sA + (16 * et + li) * PAD_N + 32 * kt + 8 * q);
            acc[0][et] = mfma16(A1[0][kt], b, acc[0][et]);
            acc[1][et] = mfma16(A1[1][kt], b, acc[1][et]);
        }
    }
    __syncthreads();                                  // S2: sA reads done (alias!)

    // ---- A2 -> registers ----
    f16x8 A2[2][4];
#pragma unroll
    for (int ht = 0; ht < 2; ++ht)
#pragma unroll
        for (int kt = 0; kt < 4; ++kt)
            A2[ht][kt] = *(const f16x8*)(w2p + ((size_t)(kt * 8 + wv * 2 + ht) * 64 + l) * 8);

    // ---- epilogue1: +b1, relu -> sT (aliases sA) ----
    f16* sT = sA;
#pragma unroll
    for (int ht = 0; ht < 2; ++ht) {
        const int hidb = 32 * wv + 16 * ht + 4 * q;
        const float4 bb = *(const float4*)(b1 + hidb);
#pragma unroll
        for (int et = 0; et < 8; ++et) {
            const f32x4 v = acc[ht][et];
            float x0 = fmaxf(v[0] + bb.x, 0.f), x1 = fmaxf(v[1] + bb.y, 0.f);
            float x2 = fmaxf(v[2] + bb.z, 0.f), x3 = fmaxf(v[3] + bb.w, 0.f);
            f16x4 o; o[0] = (f16)x0; o[1] = (f16)x1; o[2] = (f16)x2; o[3] = (f16)x3;
            *(f16x4*)(sT + (16 * et + li) * PAD_T + hidb) = o;
        }
    }
    __syncthreads();                                  // S3: sT ready

    // ---- GEMM2: K=128 ----
    f32x4 acc2[2][8];
#pragma unroll
    for (int i = 0; i < 2; ++i)
#pragma unroll
        for (int j = 0; j < 8; ++j) acc2[i][j] = (f32x4){0.f, 0.f, 0.f, 0.f};
#pragma unroll
    for (int kt = 0; kt < 4; ++kt) {
#pragma unroll
        for (int et = 0; et < 8; ++et) {
            const f16x8 b = *(const f16x8*)(sT + (16 * et + li) * PAD_T + 32 * kt + 8 * q);
            acc2[0][et] = mfma16(A2[0][kt], b, acc2[0][et]);
            acc2[1][et] = mfma16(A2[1][kt], b, acc2[1][et]);
        }
    }
    __syncthreads();                                  // S4: sT reads done

    // ---- epilogue2: x = upd + b2 + h -> sX f32 (aliases sA) ----
    float* sX = (float*)sA;            // stride 132 f32
#pragma unroll
    for (int ht = 0; ht < 2; ++ht) {
        const int hidb = 32 * wv + 16 * ht + 4 * q;
        const float4 bb = *(const float4*)(b2 + hidb);
#pragma unroll
        for (int et = 0; et < 8; ++et) {
            const int node = 16 * et + li;
            const int nc   = min(nbase + node, N - 1);
            const float4 hv = *(const float4*)(h + (size_t)nc * HD + hidb);
            const f32x4 v = acc2[ht][et];
            f32x4 x;
            x[0] = v[0] + bb.x + hv.x;
            x[1] = v[1] + bb.y + hv.y;
            x[2] = v[2] + bb.z + hv.z;
            x[3] = v[3] + bb.w + hv.w;
            *(f32x4*)(sX + (size_t)node * 132 + hidb) = x;
        }
    }
    __syncthreads();                                  // S5

    // ---- LayerNorm ----
    {
        const int node  = t >> 1;
        const int half2 = t & 1;
        const float* px = sX + node * 132 + half2 * 64;
        float s = 0.f, sq = 0.f;
#pragma unroll
        for (int i = 0; i < 16; ++i) {
            const float4 v = *(const float4*)(px + i * 4);
            s  += v.x + v.y + v.z + v.w;
            sq += v.x * v.x + v.y * v.y + v.z * v.z + v.w * v.w;
        }
        s  += __shfl_xor(s, 1);
        sq += __shfl_xor(sq, 1);
        if (!half2) {
            const float mean = s * (1.f / HD);
            const float var  = sq * (1.f / HD) - mean * mean;
            sMV[node]       = mean;
            sMV[BMN + node] = rsqrtf(var + 1e-5f);
        }
    }
    __syncthreads();                                  // S6

#pragma unroll
    for (int i = 0; i < 16; ++i) {
        const int idx  = t + i * 256;
        const int node = idx >> 5;
        const int c4   = (idx & 31) * 4;
        if (nbase + node < N) {
            const float4 xv = *(const float4*)(sX + node * 132 + c4);
            const float4 g4 = *(const float4*)(gamma + c4);
            const float4 b4 = *(const float4*)(beta + c4);
            const float mean = sMV[node];
            const float rstd = sMV[BMN + node];
            float4 o;
            o.x = (xv.x - mean) * rstd * g4.x + b4.x;
            o.y = (xv.y - mean) * rstd * g4.y + b4.y;
            o.z = (xv.z - mean) * rstd * g4.z + b4.z;
            o.w = (xv.w - mean) * rstd * g4.w + b4.w;
            *(float4*)(out + (size_t)(nbase + node) * HD + c4) = o;
        }
    }
}

// ---------------------------------------------------------------- launch
extern "C" void kernel_launch(void* const* d_in, const int* in_sizes, int n_in,
                              void* d_out, int out_size, void* d_ws, size_t ws_size,
                              hipStream_t stream)
{
    const float* h     = (const float*)d_in[0];
    const int*   eidx  = (const int*)  d_in[1];
    const float* ea    = (const float*)d_in[2];
    const float* ew1   = (const float*)d_in[3];
    const float* eb1   = (const float*)d_in[4];
    const float* ew2   = (const float*)d_in[5];
    const float* eb2   = (const float*)d_in[6];
    const float* nw1   = (const float*)d_in[7];
    const float* nb1   = (const float*)d_in[8];
    const float* nw2   = (const float*)d_in[9];
    const float* nb2   = (const float*)d_in[10];
    const float* gamma = (const float*)d_in[11];
    const float* beta  = (const float*)d_in[12];
    float* out = (float*)d_out;

    const int N = in_sizes[0] / HD;
    const int E = in_sizes[1] / 2;
    const int ntiles = (E + BME - 1) / BME;

    size_t off = 0;
    auto alloc = [&](size_t bytes) {
        size_t o = off; off += (bytes + 255) & ~(size_t)255; return o;
    };
    const size_t o_m    = alloc((size_t)E * HD * sizeof(f16));
    const size_t o_h16  = alloc((size_t)N * HD * sizeof(f16));
    const size_t o_pos  = alloc((size_t)E * sizeof(int));
    const size_t o_rs   = alloc((size_t)(N + 1) * sizeof(int));
    const size_t o_cnt  = alloc((size_t)N * sizeof(int));
    const size_t o_w1p  = alloc((size_t)9 * 8 * 64 * 8 * sizeof(f16));
    const size_t o_w2p  = alloc((size_t)4 * 8 * 64 * 8 * sizeof(f16));
    const size_t o_n1p  = alloc((size_t)8 * 8 * 64 * 8 * sizeof(f16));
    const size_t o_n2p  = alloc((size_t)4 * 8 * 64 * 8 * sizeof(f16));
    const bool csr = (off <= ws_size);
    char* ws = (char*)d_ws;

    if (csr) {
        f16* mb   = (f16*)(ws + o_m);
        f16* h16  = (f16*)(ws + o_h16);
        int* pos  = (int*)(ws + o_pos);
        int* rs   = (int*)(ws + o_rs);
        int* cnt  = (int*)(ws + o_cnt);
        f16* w1p  = (f16*)(ws + o_w1p);
        f16* w2p  = (f16*)(ws + o_w2p);
        f16* n1p  = (f16*)(ws + o_n1p);
        f16* n2p  = (f16*)(ws + o_n2p);

        zero_i32<<<(N + 255) / 256, 256, 0, stream>>>(cnt, N);
        hist_kernel<<<(E + 255) / 256, 256, 0, stream>>>(eidx, pos, cnt, E);
        scan_kernel<<<1, 1024, 0, stream>>>(cnt, rs, N);
        pos_kernel<<<(E + 255) / 256, 256, 0, stream>>>(eidx, rs, pos, E);
        cvt_f16_kernel<<<2048, 256, 0, stream>>>(h, h16, (long)N * HD / 8);
        pack_all_kernel<<<50, 256, 0, stream>>>(ew1, ew2, nw1, nw2, w1p, w2p, n1p, n2p);
        edge_kernel<1><<<EGRID, 512, 0, stream>>>(
            h16, eidx, ea, w1p, eb1, w2p, eb2, (void*)mb, pos, E, ntiles);
        node_kernel<1><<<(N + BMN - 1) / BMN, 256, 0, stream>>>(
            h16, h, mb, rs, nullptr, n1p, nb1, n2p, nb2, gamma, beta, out, N);
    } else {
        // fallback: dense f32 atomic aggregation
        size_t foff = 0;
        auto falloc = [&](size_t bytes) {
            size_t o = foff; foff += (bytes + 255) & ~(size_t)255; return o;
        };
        float* agg = (float*)(ws + falloc((size_t)N * HD * sizeof(float)));
        f16*   h16 = (f16*)  (ws + falloc((size_t)N * HD * sizeof(f16)));
        f16*   w1p = (f16*)  (ws + falloc((size_t)9 * 8 * 64 * 8 * sizeof(f16)));
        f16*   w2p = (f16*)  (ws + falloc((size_t)4 * 8 * 64 * 8 * sizeof(f16)));
        f16*   n1p = (f16*)  (ws + falloc((size_t)8 * 8 * 64 * 8 * sizeof(f16)));
        f16*   n2p = (f16*)  (ws + falloc((size_t)4 * 8 * 64 * 8 * sizeof(f16)));

        zero_f32<<<1024, 256, 0, stream>>>((float4*)agg, (long)N * HD / 4);
        cvt_f16_kernel<<<2048, 256, 0, stream>>>(h, h16, (long)N * HD / 8);
        pack_all_kernel<<<50, 256, 0, stream>>>(ew1, ew2, nw1, nw2, w1p, w2p, n1p, n2p);
        edge_kernel<0><<<EGRID, 512, 0, stream>>>(
            h16, eidx, ea, w1p, eb1, w2p, eb2, (void*)agg, nullptr, E, ntiles);
        node_kernel<0><<<(N + BMN - 1) / BMN, 256, 0, stream>>>(
            h16, h, nullptr, nullptr, agg, n1p, nb1, n2p, nb2, gamma, beta, out, N);
    }
}